// Round 8
// baseline (766.440 us; speedup 1.0000x reference)
//
#include <hip/hip_runtime.h>
#include <hip/hip_bf16.h>
#include <hip/hip_cooperative_groups.h>
#include <cstdint>

namespace cg = cooperative_groups;

#define N_NODES 50000
#define N_EDGES 1600000
#define DIM 128
#define NREL 8
#define LN_EPS 1e-5f

#define NKEYS (N_NODES * NREL)          // 400000
#define SCAN_CHUNK 1024                 // keys per scan block (256 thr x 4)
#define SCAN_NBLK ((NKEYS + SCAN_CHUNK - 1) / SCAN_CHUNK)  // 391

#define A_STRIDE 136                    // ushorts per LDS A row (128 + 8 pad)
#define B_STRIDE 136                    // ushorts per LDS B row

#define BUILD_BLOCKS 1024

typedef unsigned short ushort_t;
typedef short short8 __attribute__((ext_vector_type(8)));
typedef float f32x4 __attribute__((ext_vector_type(4)));
typedef unsigned uintx4 __attribute__((ext_vector_type(4)));

__device__ inline ushort_t f2bf(float f) {
    union { float f; unsigned u; } v; v.f = f;
    unsigned r = (v.u + 0x7FFFu + ((v.u >> 16) & 1u)) >> 16;
    return (ushort_t)r;
}
__device__ inline float bf_lo(unsigned u) {
    union { unsigned u; float f; } v; v.u = u << 16;
    return v.f;
}
__device__ inline float bf_hi(unsigned u) {
    union { unsigned u; float f; } v; v.u = u & 0xffff0000u;
    return v.f;
}

// ---------------------------------------------------------------------------
// Cooperative build: zero cnt + prep xb/Bt | count+rank | scan1 | scan2 | fill
// All in one launch; grid.sync() between phases. 1024 blocks x 256.
// ---------------------------------------------------------------------------
__global__ __launch_bounds__(256) void build_kernel(const float* __restrict__ x,
                                                    ushort_t* __restrict__ xb,
                                                    const float* __restrict__ W_rel,
                                                    const float* __restrict__ W_root,
                                                    ushort_t* __restrict__ Bt,
                                                    const int* __restrict__ ei,
                                                    const int* __restrict__ et,
                                                    unsigned* __restrict__ cnt,
                                                    unsigned* __restrict__ krk,
                                                    uint2* __restrict__ meta,
                                                    unsigned* __restrict__ bsums,
                                                    int* __restrict__ sorted_src) {
    cg::grid_group grid = cg::this_grid();
    __shared__ unsigned sh[256];
    const int gtid = blockIdx.x * 256 + threadIdx.x;
    const int gsz  = gridDim.x * 256;

    // ---- phase 0: zero cnt; x -> xb (bf16); W -> Bt (transposed bf16) ----
    for (int i = gtid; i < NKEYS; i += gsz) cnt[i] = 0u;
    for (int i = gtid; i < N_NODES * DIM / 4; i += gsz) {
        float4 v = ((const float4*)x)[i];
        unsigned lo = (unsigned)f2bf(v.x) | ((unsigned)f2bf(v.y) << 16);
        unsigned hi = (unsigned)f2bf(v.z) | ((unsigned)f2bf(v.w) << 16);
        ((uint2*)xb)[i] = make_uint2(lo, hi);
    }
    for (int i = gtid; i < 9 * DIM * DIM; i += gsz) {
        int r   = i >> 14;
        int rem = i & 16383;
        int n   = rem >> 7;
        int k   = rem & 127;
        const float* W = (r < NREL) ? (W_rel + (size_t)r * DIM * DIM) : W_root;
        Bt[i] = f2bf(W[(size_t)k * DIM + n]);
    }
    grid.sync();

    // ---- phase 1: count + within-bucket rank, packed (key<<13 | rank) ----
    for (int e = gtid; e < N_EDGES; e += gsz) {
        int dst = ei[N_EDGES + e];
        unsigned key = (unsigned)dst * NREL + (unsigned)et[e];
        unsigned rank = atomicAdd(&cnt[key], 1u);
        krk[e] = (key << 13) | rank;
    }
    grid.sync();

    // ---- phase 2: block-local exclusive scan -> meta, block sums ----
    if (blockIdx.x < SCAN_NBLK) {
        int tid = threadIdx.x;
        int i0  = blockIdx.x * SCAN_CHUNK + tid * 4;
        unsigned v[4], incl[4];
        unsigned s = 0;
#pragma unroll
        for (int j = 0; j < 4; ++j) {
            v[j] = (i0 + j < NKEYS) ? cnt[i0 + j] : 0u;
            s += v[j];
            incl[j] = s;
        }
        sh[tid] = s;
        __syncthreads();
        for (int off = 1; off < 256; off <<= 1) {
            unsigned a = (tid >= off) ? sh[tid - off] : 0u;
            __syncthreads();
            sh[tid] += a;
            __syncthreads();
        }
        unsigned base = sh[tid] - s;
#pragma unroll
        for (int j = 0; j < 4; ++j) {
            if (i0 + j < NKEYS) meta[i0 + j] = make_uint2(base + incl[j] - v[j], v[j]);
        }
        if (tid == 255) bsums[blockIdx.x] = sh[255];
    }
    grid.sync();

    // ---- phase 3: exclusive scan of 391 block sums (block 0, 2/thread) ----
    if (blockIdx.x == 0) {
        int t = threadIdx.x;
        unsigned a = (2 * t     < SCAN_NBLK) ? bsums[2 * t]     : 0u;
        unsigned b = (2 * t + 1 < SCAN_NBLK) ? bsums[2 * t + 1] : 0u;
        unsigned s = a + b;
        __syncthreads();
        sh[t] = s;
        __syncthreads();
        for (int off = 1; off < 256; off <<= 1) {
            unsigned u = (t >= off) ? sh[t - off] : 0u;
            __syncthreads();
            sh[t] += u;
            __syncthreads();
        }
        unsigned base = sh[t] - s;
        if (2 * t     < SCAN_NBLK) bsums[2 * t]     = base;
        if (2 * t + 1 < SCAN_NBLK) bsums[2 * t + 1] = base + a;
    }
    grid.sync();

    // ---- phase 4: atomic-free counting-sort fill ----
    for (int e = gtid; e < N_EDGES; e += gsz) {
        unsigned kr   = krk[e];
        unsigned key  = kr >> 13;
        unsigned rank = kr & 8191u;
        unsigned p = meta[key].x + bsums[key >> 10] + rank;
        sorted_src[p] = ei[e];
    }
}

// ---------------------------------------------------------------------------
// Quarter-wave (16 lanes x 16B) per (node, rel) bucket: mean of xb rows -> h.
// Nontemporal h stores (write-once; keep xb L2-resident).
// ---------------------------------------------------------------------------
__global__ __launch_bounds__(256) void aggregate_kernel(const uint2* __restrict__ meta,
                                                        const unsigned* __restrict__ bsums,
                                                        const int* __restrict__ sorted_src,
                                                        const ushort_t* __restrict__ xb,
                                                        ushort_t* __restrict__ h,
                                                        int r0, int cr) {
    int g  = blockIdx.x * 16 + (threadIdx.x >> 4);   // bucket id
    int sl = threadIdx.x & 15;                       // lane covers 8 feats
    int total = N_NODES * cr;
    if (g >= total) return;
    unsigned key;
    if (cr == NREL) {
        key = (unsigned)g;                           // g == node*8 + rel
    } else {
        int n  = g / cr;
        int rl = g - n * cr;
        key = (unsigned)n * NREL + r0 + rl;
    }
    uint2 md = meta[key];
    unsigned st = md.x + bsums[key >> 10];
    unsigned mc = md.y;
    unsigned en = st + mc;
    float a0 = 0.f, a1 = 0.f, a2 = 0.f, a3 = 0.f;
    float a4 = 0.f, a5 = 0.f, a6 = 0.f, a7 = 0.f;
    unsigned e = st;
    for (; e + 1 < en; e += 2) {
        int s0 = sorted_src[e];
        int s1 = sorted_src[e + 1];
        uintx4 d0 = *(const uintx4*)(xb + (size_t)s0 * DIM + sl * 8);
        uintx4 d1 = *(const uintx4*)(xb + (size_t)s1 * DIM + sl * 8);
        a0 += bf_lo(d0.x) + bf_lo(d1.x);
        a1 += bf_hi(d0.x) + bf_hi(d1.x);
        a2 += bf_lo(d0.y) + bf_lo(d1.y);
        a3 += bf_hi(d0.y) + bf_hi(d1.y);
        a4 += bf_lo(d0.z) + bf_lo(d1.z);
        a5 += bf_hi(d0.z) + bf_hi(d1.z);
        a6 += bf_lo(d0.w) + bf_lo(d1.w);
        a7 += bf_hi(d0.w) + bf_hi(d1.w);
    }
    if (e < en) {
        int s0 = sorted_src[e];
        uintx4 d0 = *(const uintx4*)(xb + (size_t)s0 * DIM + sl * 8);
        a0 += bf_lo(d0.x);
        a1 += bf_hi(d0.x);
        a2 += bf_lo(d0.y);
        a3 += bf_hi(d0.y);
        a4 += bf_lo(d0.z);
        a5 += bf_hi(d0.z);
        a6 += bf_lo(d0.w);
        a7 += bf_hi(d0.w);
    }
    float inv = 1.0f / fmaxf((float)mc, 1.0f);
    uintx4 o;
    o.x = (unsigned)f2bf(a0 * inv) | ((unsigned)f2bf(a1 * inv) << 16);
    o.y = (unsigned)f2bf(a2 * inv) | ((unsigned)f2bf(a3 * inv) << 16);
    o.z = (unsigned)f2bf(a4 * inv) | ((unsigned)f2bf(a5 * inv) << 16);
    o.w = (unsigned)f2bf(a6 * inv) | ((unsigned)f2bf(a7 * inv) << 16);
    __builtin_nontemporal_store(o, (uintx4*)(h + (size_t)g * DIM) + sl);
}

// ---------------------------------------------------------------------------
// LDS-staged MFMA GEMM + optional fused bias+LN+ReLU. 64 nodes x 128 feats,
// 4 waves, ~52 KB LDS, 3 blocks/CU. h staged with nontemporal loads.
// ---------------------------------------------------------------------------
__global__ __launch_bounds__(256) void gemm_ln_kernel(const ushort_t* __restrict__ h,
                                                      int cr, int r0,
                                                      const ushort_t* __restrict__ xb,
                                                      const ushort_t* __restrict__ Bt,
                                                      int include_root,
                                                      const float* __restrict__ bias,
                                                      const float* __restrict__ gamma,
                                                      const float* __restrict__ beta,
                                                      float* __restrict__ out,
                                                      int accumulate, int do_ln) {
    __shared__ __align__(16) ushort_t As[64 * A_STRIDE];
    __shared__ __align__(16) ushort_t Bs[128 * B_STRIDE];

    int tid  = threadIdx.x;
    int w    = tid >> 6;
    int lane = tid & 63;
    int m    = lane & 15;
    int quad = lane >> 4;
    int n0   = blockIdx.x * 64;

    f32x4 acc[8];
#pragma unroll
    for (int j = 0; j < 8; ++j) acc[j] = (f32x4){0.f, 0.f, 0.f, 0.f};

    int nrel = cr + include_root;
    for (int rr = 0; rr < nrel; ++rr) {
        int rel = (rr < cr) ? (r0 + rr) : NREL;

        // ---- stage B: 2048 x 16B chunks, 8 per thread (batched) ----
#pragma unroll
        for (int p = 0; p < 8; ++p) {
            int c = tid + 256 * p;
            int row = c >> 4, ch = c & 15;
            uintx4 v = *(const uintx4*)(Bt + ((size_t)rel * DIM + row) * DIM + ch * 8);
            *(uintx4*)&Bs[row * B_STRIDE + ch * 8] = v;
        }
        // ---- stage A: 1024 x 16B chunks, 4 per thread (batched) ----
#pragma unroll
        for (int p = 0; p < 4; ++p) {
            int c = tid + 256 * p;
            int row = c >> 4, ch = c & 15;
            uintx4 v = (uintx4){0u, 0u, 0u, 0u};
            int node = n0 + row;
            if (node < N_NODES) {
                if (rr < cr) {
                    v = __builtin_nontemporal_load(
                        (const uintx4*)(h + ((size_t)node * cr + rr) * DIM + ch * 8));
                } else {
                    v = *(const uintx4*)(xb + (size_t)node * DIM + ch * 8);
                }
            }
            *(uintx4*)&As[row * A_STRIDE + ch * 8] = v;
        }
        __syncthreads();

        // ---- 32 MFMA per wave ----
#pragma unroll
        for (int t = 0; t < 4; ++t) {
            short8 af = *(const short8*)&As[(w * 16 + m) * A_STRIDE + t * 32 + quad * 8];
#pragma unroll
            for (int j = 0; j < 8; ++j) {
                short8 bf = *(const short8*)&Bs[(j * 16 + m) * B_STRIDE + t * 32 + quad * 8];
                acc[j] = __builtin_amdgcn_mfma_f32_16x16x32_bf16(af, bf, acc[j], 0, 0, 0);
            }
        }
        __syncthreads();
    }

    // ---- epilogue ----
    if (do_ln) {
        float bj[8], gj[8], btj[8];
#pragma unroll
        for (int j = 0; j < 8; ++j) {
            bj[j]  = bias[j * 16 + m];
            gj[j]  = gamma[j * 16 + m];
            btj[j] = beta[j * 16 + m];
        }
#pragma unroll
        for (int i = 0; i < 4; ++i) {
            float s = 0.f, sq = 0.f;
#pragma unroll
            for (int j = 0; j < 8; ++j) {
                float v = acc[j][i] + bj[j];
                s  += v;
                sq += v * v;
            }
#pragma unroll
            for (int off = 1; off < 16; off <<= 1) {
                s  += __shfl_xor(s, off, 64);
                sq += __shfl_xor(sq, off, 64);
            }
            float mean = s * (1.0f / DIM);
            float var  = sq * (1.0f / DIM) - mean * mean;
            float rstd = rsqrtf(var + LN_EPS);
            int node = n0 + w * 16 + quad * 4 + i;
            if (node < N_NODES) {
#pragma unroll
                for (int j = 0; j < 8; ++j) {
                    float v = acc[j][i] + bj[j];
                    v = (v - mean) * rstd * gj[j] + btj[j];
                    out[(size_t)node * DIM + j * 16 + m] = fmaxf(v, 0.f);
                }
            }
        }
    } else {
#pragma unroll
        for (int i = 0; i < 4; ++i) {
            int node = n0 + w * 16 + quad * 4 + i;
            if (node < N_NODES) {
#pragma unroll
                for (int j = 0; j < 8; ++j) {
                    size_t o = (size_t)node * DIM + j * 16 + m;
                    float v = acc[j][i];
                    if (accumulate) v += out[o];
                    out[o] = v;
                }
            }
        }
    }
}

// ---------------------------------------------------------------------------
// Standalone bias + LayerNorm + ReLU (fallback for chunked path).
// ---------------------------------------------------------------------------
__global__ __launch_bounds__(256) void ln_kernel(float* __restrict__ out,
                                                 const float* __restrict__ bias,
                                                 const float* __restrict__ gamma,
                                                 const float* __restrict__ beta) {
    int row  = blockIdx.x * 4 + (threadIdx.x >> 6);
    int lane = threadIdx.x & 63;
    if (row >= N_NODES) return;
    float2 v = *(float2*)(out + (size_t)row * DIM + lane * 2);
    float2 bi = *(const float2*)(bias + lane * 2);
    v.x += bi.x;
    v.y += bi.y;
    float s  = v.x + v.y;
    float sq = v.x * v.x + v.y * v.y;
#pragma unroll
    for (int off = 32; off > 0; off >>= 1) {
        s  += __shfl_xor(s, off, 64);
        sq += __shfl_xor(sq, off, 64);
    }
    float mean = s * (1.0f / DIM);
    float var  = sq * (1.0f / DIM) - mean * mean;
    float rstd = rsqrtf(var + LN_EPS);
    float2 g = *(const float2*)(gamma + lane * 2);
    float2 b = *(const float2*)(beta + lane * 2);
    v.x = fmaxf((v.x - mean) * rstd * g.x + b.x, 0.f);
    v.y = fmaxf((v.y - mean) * rstd * g.y + b.y, 0.f);
    *(float2*)(out + (size_t)row * DIM + lane * 2) = v;
}

// ---------------------------------------------------------------------------
extern "C" void kernel_launch(void* const* d_in, const int* in_sizes, int n_in,
                              void* d_out, int out_size, void* d_ws, size_t ws_size,
                              hipStream_t stream) {
    const float* x      = (const float*)d_in[0];
    const int*   ei     = (const int*)d_in[1];
    const int*   et     = (const int*)d_in[2];
    const float* W_rel  = (const float*)d_in[4];
    const float* W_root = (const float*)d_in[5];
    const float* bias   = (const float*)d_in[6];
    const float* gamma  = (const float*)d_in[7];
    const float* beta   = (const float*)d_in[8];
    float*       out    = (float*)d_out;

    // ---- workspace layout ----
    char* ws = (char*)d_ws;
    size_t off = 0;
    auto alloc = [&](size_t bytes) { char* p = ws + off; off = (off + bytes + 255) & ~(size_t)255; return p; };
    unsigned* cnt        = (unsigned*)alloc((size_t)NKEYS * 4);
    uint2*    meta       = (uint2*)alloc((size_t)NKEYS * 8);
    unsigned* bsums      = (unsigned*)alloc((size_t)SCAN_NBLK * 4);
    unsigned* krk        = (unsigned*)alloc((size_t)N_EDGES * 4);
    int*      sorted_src = (int*)alloc((size_t)N_EDGES * 4);
    ushort_t* Bt         = (ushort_t*)alloc((size_t)9 * DIM * DIM * 2);
    ushort_t* xb         = (ushort_t*)alloc((size_t)N_NODES * DIM * 2);
    size_t fixedOff = off;
    ushort_t* h = (ushort_t*)(ws + fixedOff);
    size_t availB = ws_size > fixedOff ? ws_size - fixedOff : 0;
    size_t perRel = (size_t)N_NODES * DIM * 2;   // 12.8 MB per relation (bf16)
    int chunkR = (int)(availB / perRel);
    if (chunkR > NREL) chunkR = NREL;
    if (chunkR < 1)    chunkR = 1;

    // ---- single cooperative build launch ----
    {
        void* args[] = { (void*)&x, (void*)&xb, (void*)&W_rel, (void*)&W_root,
                         (void*)&Bt, (void*)&ei, (void*)&et, (void*)&cnt,
                         (void*)&krk, (void*)&meta, (void*)&bsums, (void*)&sorted_src };
        hipLaunchCooperativeKernel((const void*)build_kernel,
                                   dim3(BUILD_BLOCKS), dim3(256), args, 0, stream);
    }

    int gemmGrid = (N_NODES + 63) / 64;

    if (chunkR >= NREL) {
        int nbuck = N_NODES * NREL;
        aggregate_kernel<<<(nbuck + 15) / 16, 256, 0, stream>>>(meta, bsums, sorted_src,
                                                                xb, h, 0, NREL);
        gemm_ln_kernel<<<gemmGrid, 256, 0, stream>>>(h, NREL, 0, xb, Bt, 1,
                                                     bias, gamma, beta, out, 0, 1);
    } else {
        for (int r0 = 0; r0 < NREL; r0 += chunkR) {
            int cr = (NREL - r0 < chunkR) ? (NREL - r0) : chunkR;
            int nbuck = N_NODES * cr;
            aggregate_kernel<<<(nbuck + 15) / 16, 256, 0, stream>>>(meta, bsums, sorted_src,
                                                                    xb, h, r0, cr);
            int include_root = (r0 + cr == NREL) ? 1 : 0;
            gemm_ln_kernel<<<gemmGrid, 256, 0, stream>>>(h, cr, r0, xb, Bt, include_root,
                                                         bias, gamma, beta, out,
                                                         r0 > 0 ? 1 : 0, 0);
        }
        ln_kernel<<<(N_NODES + 3) / 4, 256, 0, stream>>>(out, bias, gamma, beta);
    }
}

// Round 9
// 390.354 us; speedup vs baseline: 1.9634x; 1.9634x over previous
//
#include <hip/hip_runtime.h>
#include <hip/hip_bf16.h>
#include <cstdint>

#define N_NODES 50000
#define N_EDGES 1600000
#define DIM 128
#define NREL 8
#define LN_EPS 1e-5f

#define NKEYS (N_NODES * NREL)          // 400000
#define SCAN_CHUNK 1024                 // keys per scan block (256 thr x 4)
#define SCAN_NBLK ((NKEYS + SCAN_CHUNK - 1) / SCAN_CHUNK)  // 391

#define A_STRIDE 136                    // ushorts per LDS A row (128 + 8 pad)
#define B_STRIDE 136                    // ushorts per LDS B row

#define XB_BLOCKS 6250                  // N_NODES*DIM/4 / 256
#define BT_BLOCKS 576                   // 9*128*128 / 256
#define CNT_BLOCKS ((N_EDGES + 255) / 256)   // 6250

typedef unsigned short ushort_t;
typedef short short8 __attribute__((ext_vector_type(8)));
typedef float f32x4 __attribute__((ext_vector_type(4)));
typedef unsigned uintx4 __attribute__((ext_vector_type(4)));

__device__ inline ushort_t f2bf(float f) {
    union { float f; unsigned u; } v; v.f = f;
    unsigned r = (v.u + 0x7FFFu + ((v.u >> 16) & 1u)) >> 16;
    return (ushort_t)r;
}
__device__ inline float bf_lo(unsigned u) {
    union { unsigned u; float f; } v; v.u = u << 16;
    return v.f;
}
__device__ inline float bf_hi(unsigned u) {
    union { unsigned u; float f; } v; v.u = u & 0xffff0000u;
    return v.f;
}

// ---------------------------------------------------------------------------
// Fused prep + count: blocks [0, XB) convert x->xb; [XB, XB+BT) build Bt;
// [XB+BT, end) count edges per key and record within-bucket rank
// (key<<13 | rank). The two halves have no data dependency.
// ---------------------------------------------------------------------------
__global__ __launch_bounds__(256) void prep_count_kernel(const float* __restrict__ x,
                                                         ushort_t* __restrict__ xb,
                                                         const float* __restrict__ W_rel,
                                                         const float* __restrict__ W_root,
                                                         ushort_t* __restrict__ Bt,
                                                         const int* __restrict__ ei,
                                                         const int* __restrict__ et,
                                                         unsigned* __restrict__ cnt,
                                                         unsigned* __restrict__ krk) {
    int b = blockIdx.x;
    if (b < XB_BLOCKS) {
        int i = b * 256 + threadIdx.x;            // float4 index
        float4 v = ((const float4*)x)[i];
        unsigned lo = (unsigned)f2bf(v.x) | ((unsigned)f2bf(v.y) << 16);
        unsigned hi = (unsigned)f2bf(v.z) | ((unsigned)f2bf(v.w) << 16);
        ((uint2*)xb)[i] = make_uint2(lo, hi);
    } else if (b < XB_BLOCKS + BT_BLOCKS) {
        int i = (b - XB_BLOCKS) * 256 + threadIdx.x;
        int r   = i >> 14;
        int rem = i & 16383;
        int n   = rem >> 7;
        int k   = rem & 127;
        const float* W = (r < NREL) ? (W_rel + (size_t)r * DIM * DIM) : W_root;
        Bt[i] = f2bf(W[(size_t)k * DIM + n]);
    } else {
        int e = (b - XB_BLOCKS - BT_BLOCKS) * 256 + threadIdx.x;
        if (e < N_EDGES) {
            int dst = ei[N_EDGES + e];
            unsigned key = (unsigned)dst * NREL + (unsigned)et[e];
            unsigned rank = atomicAdd(&cnt[key], 1u);
            krk[e] = (key << 13) | rank;
        }
    }
}

// ---------------------------------------------------------------------------
// Block-local exclusive scan: meta[key] = (local_excl_offset, cnt), plus
// per-block sums. Consumers add bsums[key>>10] for the global offset.
// ---------------------------------------------------------------------------
__global__ __launch_bounds__(256) void scan1_kernel(const unsigned* __restrict__ cnt,
                                                    uint2* __restrict__ meta,
                                                    unsigned* __restrict__ bsums) {
    __shared__ unsigned lds[256];
    int tid = threadIdx.x;
    int i0  = blockIdx.x * SCAN_CHUNK + tid * 4;
    unsigned v[4], incl[4];
    unsigned s = 0;
#pragma unroll
    for (int j = 0; j < 4; ++j) {
        v[j] = (i0 + j < NKEYS) ? cnt[i0 + j] : 0u;
        s += v[j];
        incl[j] = s;
    }
    lds[tid] = s;
    __syncthreads();
    for (int off = 1; off < 256; off <<= 1) {
        unsigned a = (tid >= off) ? lds[tid - off] : 0u;
        __syncthreads();
        lds[tid] += a;
        __syncthreads();
    }
    unsigned base = lds[tid] - s;
#pragma unroll
    for (int j = 0; j < 4; ++j) {
        if (i0 + j < NKEYS) meta[i0 + j] = make_uint2(base + incl[j] - v[j], v[j]);
    }
    if (tid == 255) bsums[blockIdx.x] = lds[255];
}

__global__ __launch_bounds__(512) void scan2_kernel(unsigned* __restrict__ bsums) {
    __shared__ unsigned lds[512];
    int tid = threadIdx.x;
    unsigned v = (tid < SCAN_NBLK) ? bsums[tid] : 0u;
    lds[tid] = v;
    __syncthreads();
    for (int off = 1; off < 512; off <<= 1) {
        unsigned a = (tid >= off) ? lds[tid - off] : 0u;
        __syncthreads();
        lds[tid] += a;
        __syncthreads();
    }
    if (tid < SCAN_NBLK) bsums[tid] = lds[tid] - v;
}

// ---------------------------------------------------------------------------
// Atomic-free counting-sort fill: p = meta[key].x + bsums[key>>10] + rank.
// ---------------------------------------------------------------------------
__global__ __launch_bounds__(256) void fill_kernel(const int* __restrict__ ei,
                                                   const unsigned* __restrict__ krk,
                                                   const uint2* __restrict__ meta,
                                                   const unsigned* __restrict__ bsums,
                                                   int* __restrict__ sorted_src) {
    int e = blockIdx.x * 256 + threadIdx.x;
    if (e < N_EDGES) {
        unsigned kr   = krk[e];
        unsigned key  = kr >> 13;
        unsigned rank = kr & 8191u;
        unsigned p = meta[key].x + bsums[key >> 10] + rank;
        sorted_src[p] = ei[e];
    }
}

// ---------------------------------------------------------------------------
// One wave per (node, rel) bucket, lanes = 4 edge-slots x 16 feat-chunks:
// each loop iteration covers 4 edges with 4 independent 16B loads in flight.
// 2-step shfl_xor (16,32) reduction, then lanes sub==0 write h (nontemporal).
// ---------------------------------------------------------------------------
__global__ __launch_bounds__(256) void aggregate_kernel(const uint2* __restrict__ meta,
                                                        const unsigned* __restrict__ bsums,
                                                        const int* __restrict__ sorted_src,
                                                        const ushort_t* __restrict__ xb,
                                                        ushort_t* __restrict__ h,
                                                        int r0, int cr) {
    int g    = blockIdx.x * 4 + (threadIdx.x >> 6);   // bucket id
    int lane = threadIdx.x & 63;
    int sub  = lane >> 4;                             // edge slot 0..3
    int sl   = lane & 15;                             // feat chunk (8 feats)
    int total = N_NODES * cr;
    if (g >= total) return;
    unsigned key;
    if (cr == NREL) {
        key = (unsigned)g;                            // g == node*8 + rel
    } else {
        int n  = g / cr;
        int rl = g - n * cr;
        key = (unsigned)n * NREL + r0 + rl;
    }
    uint2 md = meta[key];
    unsigned st = md.x + bsums[key >> 10];
    unsigned mc = md.y;
    unsigned en = st + mc;

    float a0 = 0.f, a1 = 0.f, a2 = 0.f, a3 = 0.f;
    float a4 = 0.f, a5 = 0.f, a6 = 0.f, a7 = 0.f;
    for (unsigned e = st + sub; e < en; e += 4) {
        int s0 = sorted_src[e];
        uintx4 d = *(const uintx4*)(xb + (size_t)s0 * DIM + sl * 8);
        a0 += bf_lo(d.x);
        a1 += bf_hi(d.x);
        a2 += bf_lo(d.y);
        a3 += bf_hi(d.y);
        a4 += bf_lo(d.z);
        a5 += bf_hi(d.z);
        a6 += bf_lo(d.w);
        a7 += bf_hi(d.w);
    }
    // reduce across the 4 edge-slot groups (lanes differing in bits 4,5)
#pragma unroll
    for (int msk = 16; msk <= 32; msk <<= 1) {
        a0 += __shfl_xor(a0, msk, 64);
        a1 += __shfl_xor(a1, msk, 64);
        a2 += __shfl_xor(a2, msk, 64);
        a3 += __shfl_xor(a3, msk, 64);
        a4 += __shfl_xor(a4, msk, 64);
        a5 += __shfl_xor(a5, msk, 64);
        a6 += __shfl_xor(a6, msk, 64);
        a7 += __shfl_xor(a7, msk, 64);
    }
    if (sub == 0) {
        float inv = 1.0f / fmaxf((float)mc, 1.0f);
        uintx4 o;
        o.x = (unsigned)f2bf(a0 * inv) | ((unsigned)f2bf(a1 * inv) << 16);
        o.y = (unsigned)f2bf(a2 * inv) | ((unsigned)f2bf(a3 * inv) << 16);
        o.z = (unsigned)f2bf(a4 * inv) | ((unsigned)f2bf(a5 * inv) << 16);
        o.w = (unsigned)f2bf(a6 * inv) | ((unsigned)f2bf(a7 * inv) << 16);
        __builtin_nontemporal_store(o, (uintx4*)(h + (size_t)g * DIM) + sl);
    }
}

// ---------------------------------------------------------------------------
// LDS-staged MFMA GEMM + optional fused bias+LN+ReLU. 64 nodes x 128 feats,
// 4 waves, ~52 KB LDS, 3 blocks/CU. h staged with nontemporal loads.
// ---------------------------------------------------------------------------
__global__ __launch_bounds__(256) void gemm_ln_kernel(const ushort_t* __restrict__ h,
                                                      int cr, int r0,
                                                      const ushort_t* __restrict__ xb,
                                                      const ushort_t* __restrict__ Bt,
                                                      int include_root,
                                                      const float* __restrict__ bias,
                                                      const float* __restrict__ gamma,
                                                      const float* __restrict__ beta,
                                                      float* __restrict__ out,
                                                      int accumulate, int do_ln) {
    __shared__ __align__(16) ushort_t As[64 * A_STRIDE];
    __shared__ __align__(16) ushort_t Bs[128 * B_STRIDE];

    int tid  = threadIdx.x;
    int w    = tid >> 6;
    int lane = tid & 63;
    int m    = lane & 15;
    int quad = lane >> 4;
    int n0   = blockIdx.x * 64;

    f32x4 acc[8];
#pragma unroll
    for (int j = 0; j < 8; ++j) acc[j] = (f32x4){0.f, 0.f, 0.f, 0.f};

    int nrel = cr + include_root;
    for (int rr = 0; rr < nrel; ++rr) {
        int rel = (rr < cr) ? (r0 + rr) : NREL;

        // ---- stage B: 2048 x 16B chunks, 8 per thread (batched) ----
#pragma unroll
        for (int p = 0; p < 8; ++p) {
            int c = tid + 256 * p;
            int row = c >> 4, ch = c & 15;
            uintx4 v = *(const uintx4*)(Bt + ((size_t)rel * DIM + row) * DIM + ch * 8);
            *(uintx4*)&Bs[row * B_STRIDE + ch * 8] = v;
        }
        // ---- stage A: 1024 x 16B chunks, 4 per thread (batched) ----
#pragma unroll
        for (int p = 0; p < 4; ++p) {
            int c = tid + 256 * p;
            int row = c >> 4, ch = c & 15;
            uintx4 v = (uintx4){0u, 0u, 0u, 0u};
            int node = n0 + row;
            if (node < N_NODES) {
                if (rr < cr) {
                    v = __builtin_nontemporal_load(
                        (const uintx4*)(h + ((size_t)node * cr + rr) * DIM + ch * 8));
                } else {
                    v = *(const uintx4*)(xb + (size_t)node * DIM + ch * 8);
                }
            }
            *(uintx4*)&As[row * A_STRIDE + ch * 8] = v;
        }
        __syncthreads();

        // ---- 32 MFMA per wave ----
#pragma unroll
        for (int t = 0; t < 4; ++t) {
            short8 af = *(const short8*)&As[(w * 16 + m) * A_STRIDE + t * 32 + quad * 8];
#pragma unroll
            for (int j = 0; j < 8; ++j) {
                short8 bf = *(const short8*)&Bs[(j * 16 + m) * B_STRIDE + t * 32 + quad * 8];
                acc[j] = __builtin_amdgcn_mfma_f32_16x16x32_bf16(af, bf, acc[j], 0, 0, 0);
            }
        }
        __syncthreads();
    }

    // ---- epilogue ----
    if (do_ln) {
        float bj[8], gj[8], btj[8];
#pragma unroll
        for (int j = 0; j < 8; ++j) {
            bj[j]  = bias[j * 16 + m];
            gj[j]  = gamma[j * 16 + m];
            btj[j] = beta[j * 16 + m];
        }
#pragma unroll
        for (int i = 0; i < 4; ++i) {
            float s = 0.f, sq = 0.f;
#pragma unroll
            for (int j = 0; j < 8; ++j) {
                float v = acc[j][i] + bj[j];
                s  += v;
                sq += v * v;
            }
#pragma unroll
            for (int off = 1; off < 16; off <<= 1) {
                s  += __shfl_xor(s, off, 64);
                sq += __shfl_xor(sq, off, 64);
            }
            float mean = s * (1.0f / DIM);
            float var  = sq * (1.0f / DIM) - mean * mean;
            float rstd = rsqrtf(var + LN_EPS);
            int node = n0 + w * 16 + quad * 4 + i;
            if (node < N_NODES) {
#pragma unroll
                for (int j = 0; j < 8; ++j) {
                    float v = acc[j][i] + bj[j];
                    v = (v - mean) * rstd * gj[j] + btj[j];
                    out[(size_t)node * DIM + j * 16 + m] = fmaxf(v, 0.f);
                }
            }
        }
    } else {
#pragma unroll
        for (int i = 0; i < 4; ++i) {
            int node = n0 + w * 16 + quad * 4 + i;
            if (node < N_NODES) {
#pragma unroll
                for (int j = 0; j < 8; ++j) {
                    size_t o = (size_t)node * DIM + j * 16 + m;
                    float v = acc[j][i];
                    if (accumulate) v += out[o];
                    out[o] = v;
                }
            }
        }
    }
}

// ---------------------------------------------------------------------------
// Standalone bias + LayerNorm + ReLU (fallback for chunked path).
// ---------------------------------------------------------------------------
__global__ __launch_bounds__(256) void ln_kernel(float* __restrict__ out,
                                                 const float* __restrict__ bias,
                                                 const float* __restrict__ gamma,
                                                 const float* __restrict__ beta) {
    int row  = blockIdx.x * 4 + (threadIdx.x >> 6);
    int lane = threadIdx.x & 63;
    if (row >= N_NODES) return;
    float2 v = *(float2*)(out + (size_t)row * DIM + lane * 2);
    float2 bi = *(const float2*)(bias + lane * 2);
    v.x += bi.x;
    v.y += bi.y;
    float s  = v.x + v.y;
    float sq = v.x * v.x + v.y * v.y;
#pragma unroll
    for (int off = 32; off > 0; off >>= 1) {
        s  += __shfl_xor(s, off, 64);
        sq += __shfl_xor(sq, off, 64);
    }
    float mean = s * (1.0f / DIM);
    float var  = sq * (1.0f / DIM) - mean * mean;
    float rstd = rsqrtf(var + LN_EPS);
    float2 g = *(const float2*)(gamma + lane * 2);
    float2 b = *(const float2*)(beta + lane * 2);
    v.x = fmaxf((v.x - mean) * rstd * g.x + b.x, 0.f);
    v.y = fmaxf((v.y - mean) * rstd * g.y + b.y, 0.f);
    *(float2*)(out + (size_t)row * DIM + lane * 2) = v;
}

// ---------------------------------------------------------------------------
extern "C" void kernel_launch(void* const* d_in, const int* in_sizes, int n_in,
                              void* d_out, int out_size, void* d_ws, size_t ws_size,
                              hipStream_t stream) {
    const float* x      = (const float*)d_in[0];
    const int*   ei     = (const int*)d_in[1];
    const int*   et     = (const int*)d_in[2];
    const float* W_rel  = (const float*)d_in[4];
    const float* W_root = (const float*)d_in[5];
    const float* bias   = (const float*)d_in[6];
    const float* gamma  = (const float*)d_in[7];
    const float* beta   = (const float*)d_in[8];
    float*       out    = (float*)d_out;

    // ---- workspace layout ----
    char* ws = (char*)d_ws;
    size_t off = 0;
    auto alloc = [&](size_t bytes) { char* p = ws + off; off = (off + bytes + 255) & ~(size_t)255; return p; };
    unsigned* cnt        = (unsigned*)alloc((size_t)NKEYS * 4);
    uint2*    meta       = (uint2*)alloc((size_t)NKEYS * 8);
    unsigned* bsums      = (unsigned*)alloc((size_t)SCAN_NBLK * 4);
    unsigned* krk        = (unsigned*)alloc((size_t)N_EDGES * 4);
    int*      sorted_src = (int*)alloc((size_t)N_EDGES * 4);
    ushort_t* Bt         = (ushort_t*)alloc((size_t)9 * DIM * DIM * 2);
    ushort_t* xb         = (ushort_t*)alloc((size_t)N_NODES * DIM * 2);
    size_t fixedOff = off;
    ushort_t* h = (ushort_t*)(ws + fixedOff);
    size_t availB = ws_size > fixedOff ? ws_size - fixedOff : 0;
    size_t perRel = (size_t)N_NODES * DIM * 2;   // 12.8 MB per relation (bf16)
    int chunkR = (int)(availB / perRel);
    if (chunkR > NREL) chunkR = NREL;
    if (chunkR < 1)    chunkR = 1;

    // ---- build counting sort (rank recorded during count; no fill atomic) ----
    hipMemsetAsync(cnt, 0, (size_t)NKEYS * 4, stream);
    prep_count_kernel<<<XB_BLOCKS + BT_BLOCKS + CNT_BLOCKS, 256, 0, stream>>>(
        x, xb, W_rel, W_root, Bt, ei, et, cnt, krk);
    scan1_kernel<<<SCAN_NBLK, 256, 0, stream>>>(cnt, meta, bsums);
    scan2_kernel<<<1, 512, 0, stream>>>(bsums);
    fill_kernel<<<(N_EDGES + 255) / 256, 256, 0, stream>>>(ei, krk, meta, bsums, sorted_src);

    int gemmGrid = (N_NODES + 63) / 64;

    if (chunkR >= NREL) {
        int nbuck = N_NODES * NREL;
        aggregate_kernel<<<(nbuck + 3) / 4, 256, 0, stream>>>(meta, bsums, sorted_src,
                                                              xb, h, 0, NREL);
        gemm_ln_kernel<<<gemmGrid, 256, 0, stream>>>(h, NREL, 0, xb, Bt, 1,
                                                     bias, gamma, beta, out, 0, 1);
    } else {
        for (int r0 = 0; r0 < NREL; r0 += chunkR) {
            int cr = (NREL - r0 < chunkR) ? (NREL - r0) : chunkR;
            int nbuck = N_NODES * cr;
            aggregate_kernel<<<(nbuck + 3) / 4, 256, 0, stream>>>(meta, bsums, sorted_src,
                                                                  xb, h, r0, cr);
            int include_root = (r0 + cr == NREL) ? 1 : 0;
            gemm_ln_kernel<<<gemmGrid, 256, 0, stream>>>(h, cr, r0, xb, Bt, include_root,
                                                         bias, gamma, beta, out,
                                                         r0 > 0 ? 1 : 0, 0);
        }
        ln_kernel<<<(N_NODES + 3) / 4, 256, 0, stream>>>(out, bias, gamma, beta);
    }
}

// Round 10
// 389.711 us; speedup vs baseline: 1.9667x; 1.0016x over previous
//
#include <hip/hip_runtime.h>
#include <hip/hip_bf16.h>
#include <cstdint>

#define N_NODES 50000
#define N_EDGES 1600000
#define DIM 128
#define NREL 8
#define LN_EPS 1e-5f

#define NKEYS (N_NODES * NREL)          // 400000
#define SCAN_CHUNK 1024                 // keys per scan block (256 thr x 4)
#define SCAN_NBLK ((NKEYS + SCAN_CHUNK - 1) / SCAN_CHUNK)  // 391

#define A_STRIDE 136                    // ushorts per LDS A row (128 + 8 pad)
#define B_STRIDE 136                    // ushorts per LDS B row

#define XB_BLOCKS 6250                  // N_NODES*DIM/4 / 256
#define BT_BLOCKS 576                   // 9*128*128 / 256
#define CNT_BLOCKS ((N_EDGES + 255) / 256)   // 6250

typedef unsigned short ushort_t;
typedef short short8 __attribute__((ext_vector_type(8)));
typedef float f32x4 __attribute__((ext_vector_type(4)));
typedef unsigned uintx4 __attribute__((ext_vector_type(4)));

__device__ inline ushort_t f2bf(float f) {
    union { float f; unsigned u; } v; v.f = f;
    unsigned r = (v.u + 0x7FFFu + ((v.u >> 16) & 1u)) >> 16;
    return (ushort_t)r;
}
__device__ inline float bf_lo(unsigned u) {
    union { unsigned u; float f; } v; v.u = u << 16;
    return v.f;
}
__device__ inline float bf_hi(unsigned u) {
    union { unsigned u; float f; } v; v.u = u & 0xffff0000u;
    return v.f;
}

// ---------------------------------------------------------------------------
// Fused prep + count: blocks [0, XB) convert x->xb; [XB, XB+BT) build Bt;
// [XB+BT, end) count edges per key and record within-bucket rank
// (key<<13 | rank). The parts have no data dependency on each other.
// ---------------------------------------------------------------------------
__global__ __launch_bounds__(256) void prep_count_kernel(const float* __restrict__ x,
                                                         ushort_t* __restrict__ xb,
                                                         const float* __restrict__ W_rel,
                                                         const float* __restrict__ W_root,
                                                         ushort_t* __restrict__ Bt,
                                                         const int* __restrict__ ei,
                                                         const int* __restrict__ et,
                                                         unsigned* __restrict__ cnt,
                                                         unsigned* __restrict__ krk) {
    int b = blockIdx.x;
    if (b < XB_BLOCKS) {
        int i = b * 256 + threadIdx.x;            // float4 index
        float4 v = ((const float4*)x)[i];
        unsigned lo = (unsigned)f2bf(v.x) | ((unsigned)f2bf(v.y) << 16);
        unsigned hi = (unsigned)f2bf(v.z) | ((unsigned)f2bf(v.w) << 16);
        ((uint2*)xb)[i] = make_uint2(lo, hi);
    } else if (b < XB_BLOCKS + BT_BLOCKS) {
        int i = (b - XB_BLOCKS) * 256 + threadIdx.x;
        int r   = i >> 14;
        int rem = i & 16383;
        int n   = rem >> 7;
        int k   = rem & 127;
        const float* W = (r < NREL) ? (W_rel + (size_t)r * DIM * DIM) : W_root;
        Bt[i] = f2bf(W[(size_t)k * DIM + n]);
    } else {
        int e = (b - XB_BLOCKS - BT_BLOCKS) * 256 + threadIdx.x;
        if (e < N_EDGES) {
            int dst = ei[N_EDGES + e];
            unsigned key = (unsigned)dst * NREL + (unsigned)et[e];
            unsigned rank = atomicAdd(&cnt[key], 1u);
            krk[e] = (key << 13) | rank;
        }
    }
}

// ---------------------------------------------------------------------------
// Block-local exclusive scan -> meta (local offset, cnt) + per-block sums;
// the LAST block to finish (device atomic done-counter) performs the
// exclusive scan of the 391 block sums in-place (decoupled two-level scan).
// ---------------------------------------------------------------------------
__global__ __launch_bounds__(256) void scan_kernel(const unsigned* __restrict__ cnt,
                                                   uint2* __restrict__ meta,
                                                   unsigned* __restrict__ bsums,
                                                   unsigned* __restrict__ done) {
    __shared__ unsigned lds[256];
    __shared__ unsigned isLast;
    int tid = threadIdx.x;
    int i0  = blockIdx.x * SCAN_CHUNK + tid * 4;
    unsigned v[4], incl[4];
    unsigned s = 0;
#pragma unroll
    for (int j = 0; j < 4; ++j) {
        v[j] = (i0 + j < NKEYS) ? cnt[i0 + j] : 0u;
        s += v[j];
        incl[j] = s;
    }
    lds[tid] = s;
    __syncthreads();
    for (int off = 1; off < 256; off <<= 1) {
        unsigned a = (tid >= off) ? lds[tid - off] : 0u;
        __syncthreads();
        lds[tid] += a;
        __syncthreads();
    }
    unsigned base = lds[tid] - s;
#pragma unroll
    for (int j = 0; j < 4; ++j) {
        if (i0 + j < NKEYS) meta[i0 + j] = make_uint2(base + incl[j] - v[j], v[j]);
    }
    if (tid == 255) bsums[blockIdx.x] = lds[255];

    // ---- last-block fold of the top-level scan ----
    __threadfence();                       // make bsums write device-visible
    if (tid == 0) isLast = (atomicAdd(done, 1u) == (unsigned)(gridDim.x - 1));
    __syncthreads();
    if (!isLast) return;
    __threadfence();                       // acquire: see all bsums writes
    volatile unsigned* vb = (volatile unsigned*)bsums;
    unsigned a0 = (2 * tid     < SCAN_NBLK) ? vb[2 * tid]     : 0u;
    unsigned a1 = (2 * tid + 1 < SCAN_NBLK) ? vb[2 * tid + 1] : 0u;
    unsigned ss = a0 + a1;
    __syncthreads();
    lds[tid] = ss;
    __syncthreads();
    for (int off = 1; off < 256; off <<= 1) {
        unsigned u = (tid >= off) ? lds[tid - off] : 0u;
        __syncthreads();
        lds[tid] += u;
        __syncthreads();
    }
    unsigned b0 = lds[tid] - ss;
    if (2 * tid     < SCAN_NBLK) bsums[2 * tid]     = b0;
    if (2 * tid + 1 < SCAN_NBLK) bsums[2 * tid + 1] = b0 + a0;
}

// ---------------------------------------------------------------------------
// Atomic-free counting-sort fill: p = meta[key].x + bsums[key>>10] + rank.
// ---------------------------------------------------------------------------
__global__ __launch_bounds__(256) void fill_kernel(const int* __restrict__ ei,
                                                   const unsigned* __restrict__ krk,
                                                   const uint2* __restrict__ meta,
                                                   const unsigned* __restrict__ bsums,
                                                   int* __restrict__ sorted_src) {
    int e = blockIdx.x * 256 + threadIdx.x;
    if (e < N_EDGES) {
        unsigned kr   = krk[e];
        unsigned key  = kr >> 13;
        unsigned rank = kr & 8191u;
        unsigned p = meta[key].x + bsums[key >> 10] + rank;
        sorted_src[p] = ei[e];
    }
}

// ---------------------------------------------------------------------------
// Half-wave (32 lanes x 8B) per (node, rel) bucket: mean of xb rows -> h bf16.
// Edge walk unrolled 4-deep: 4 independent uint2 loads in flight per iter.
// ---------------------------------------------------------------------------
__global__ __launch_bounds__(256) void aggregate_kernel(const uint2* __restrict__ meta,
                                                        const unsigned* __restrict__ bsums,
                                                        const int* __restrict__ sorted_src,
                                                        const ushort_t* __restrict__ xb,
                                                        ushort_t* __restrict__ h,
                                                        int r0, int cr) {
    int g  = blockIdx.x * 8 + (threadIdx.x >> 5);   // bucket id
    int sl = threadIdx.x & 31;                      // lane covers 4 feats
    int total = N_NODES * cr;
    if (g >= total) return;
    unsigned key;
    if (cr == NREL) {
        key = (unsigned)g;                          // g == node*8 + rel
    } else {
        int n  = g / cr;
        int rl = g - n * cr;
        key = (unsigned)n * NREL + r0 + rl;
    }
    uint2 md = meta[key];
    unsigned st = md.x + bsums[key >> 10];
    unsigned mc = md.y;
    unsigned en = st + mc;
    float a0 = 0.f, a1 = 0.f, a2 = 0.f, a3 = 0.f;
    unsigned e = st;
    for (; e + 3 < en; e += 4) {
        int s0 = sorted_src[e];
        int s1 = sorted_src[e + 1];
        int s2 = sorted_src[e + 2];
        int s3 = sorted_src[e + 3];
        uint2 d0 = *(const uint2*)(xb + (size_t)s0 * DIM + sl * 4);
        uint2 d1 = *(const uint2*)(xb + (size_t)s1 * DIM + sl * 4);
        uint2 d2 = *(const uint2*)(xb + (size_t)s2 * DIM + sl * 4);
        uint2 d3 = *(const uint2*)(xb + (size_t)s3 * DIM + sl * 4);
        a0 += (bf_lo(d0.x) + bf_lo(d1.x)) + (bf_lo(d2.x) + bf_lo(d3.x));
        a1 += (bf_hi(d0.x) + bf_hi(d1.x)) + (bf_hi(d2.x) + bf_hi(d3.x));
        a2 += (bf_lo(d0.y) + bf_lo(d1.y)) + (bf_lo(d2.y) + bf_lo(d3.y));
        a3 += (bf_hi(d0.y) + bf_hi(d1.y)) + (bf_hi(d2.y) + bf_hi(d3.y));
    }
    if (e + 1 < en) {
        int s0 = sorted_src[e];
        int s1 = sorted_src[e + 1];
        uint2 d0 = *(const uint2*)(xb + (size_t)s0 * DIM + sl * 4);
        uint2 d1 = *(const uint2*)(xb + (size_t)s1 * DIM + sl * 4);
        a0 += bf_lo(d0.x) + bf_lo(d1.x);
        a1 += bf_hi(d0.x) + bf_hi(d1.x);
        a2 += bf_lo(d0.y) + bf_lo(d1.y);
        a3 += bf_hi(d0.y) + bf_hi(d1.y);
        e += 2;
    }
    if (e < en) {
        int s0 = sorted_src[e];
        uint2 d0 = *(const uint2*)(xb + (size_t)s0 * DIM + sl * 4);
        a0 += bf_lo(d0.x);
        a1 += bf_hi(d0.x);
        a2 += bf_lo(d0.y);
        a3 += bf_hi(d0.y);
    }
    float inv = 1.0f / fmaxf((float)mc, 1.0f);
    unsigned lo = (unsigned)f2bf(a0 * inv) | ((unsigned)f2bf(a1 * inv) << 16);
    unsigned hi = (unsigned)f2bf(a2 * inv) | ((unsigned)f2bf(a3 * inv) << 16);
    ((uint2*)(h + (size_t)g * DIM))[sl] = make_uint2(lo, hi);
}

// ---------------------------------------------------------------------------
// LDS-staged MFMA GEMM + optional fused bias+LN+ReLU. 64 nodes x 128 feats,
// 4 waves, ~52 KB LDS, 3 blocks/CU. Plain (cached) loads throughout.
// ---------------------------------------------------------------------------
__global__ __launch_bounds__(256) void gemm_ln_kernel(const ushort_t* __restrict__ h,
                                                      int cr, int r0,
                                                      const ushort_t* __restrict__ xb,
                                                      const ushort_t* __restrict__ Bt,
                                                      int include_root,
                                                      const float* __restrict__ bias,
                                                      const float* __restrict__ gamma,
                                                      const float* __restrict__ beta,
                                                      float* __restrict__ out,
                                                      int accumulate, int do_ln) {
    __shared__ __align__(16) ushort_t As[64 * A_STRIDE];
    __shared__ __align__(16) ushort_t Bs[128 * B_STRIDE];

    int tid  = threadIdx.x;
    int w    = tid >> 6;
    int lane = tid & 63;
    int m    = lane & 15;
    int quad = lane >> 4;
    int n0   = blockIdx.x * 64;

    f32x4 acc[8];
#pragma unroll
    for (int j = 0; j < 8; ++j) acc[j] = (f32x4){0.f, 0.f, 0.f, 0.f};

    int nrel = cr + include_root;
    for (int rr = 0; rr < nrel; ++rr) {
        int rel = (rr < cr) ? (r0 + rr) : NREL;

        // ---- stage B: 2048 x 16B chunks, 8 per thread (batched) ----
#pragma unroll
        for (int p = 0; p < 8; ++p) {
            int c = tid + 256 * p;
            int row = c >> 4, ch = c & 15;
            uintx4 v = *(const uintx4*)(Bt + ((size_t)rel * DIM + row) * DIM + ch * 8);
            *(uintx4*)&Bs[row * B_STRIDE + ch * 8] = v;
        }
        // ---- stage A: 1024 x 16B chunks, 4 per thread (batched) ----
#pragma unroll
        for (int p = 0; p < 4; ++p) {
            int c = tid + 256 * p;
            int row = c >> 4, ch = c & 15;
            uintx4 v = (uintx4){0u, 0u, 0u, 0u};
            int node = n0 + row;
            if (node < N_NODES) {
                const ushort_t* src = (rr < cr)
                    ? (h + ((size_t)node * cr + rr) * DIM)
                    : (xb + (size_t)node * DIM);
                v = *(const uintx4*)(src + ch * 8);
            }
            *(uintx4*)&As[row * A_STRIDE + ch * 8] = v;
        }
        __syncthreads();

        // ---- 32 MFMA per wave ----
#pragma unroll
        for (int t = 0; t < 4; ++t) {
            short8 af = *(const short8*)&As[(w * 16 + m) * A_STRIDE + t * 32 + quad * 8];
#pragma unroll
            for (int j = 0; j < 8; ++j) {
                short8 bf = *(const short8*)&Bs[(j * 16 + m) * B_STRIDE + t * 32 + quad * 8];
                acc[j] = __builtin_amdgcn_mfma_f32_16x16x32_bf16(af, bf, acc[j], 0, 0, 0);
            }
        }
        __syncthreads();
    }

    // ---- epilogue ----
    if (do_ln) {
        float bj[8], gj[8], btj[8];
#pragma unroll
        for (int j = 0; j < 8; ++j) {
            bj[j]  = bias[j * 16 + m];
            gj[j]  = gamma[j * 16 + m];
            btj[j] = beta[j * 16 + m];
        }
#pragma unroll
        for (int i = 0; i < 4; ++i) {
            float s = 0.f, sq = 0.f;
#pragma unroll
            for (int j = 0; j < 8; ++j) {
                float v = acc[j][i] + bj[j];
                s  += v;
                sq += v * v;
            }
#pragma unroll
            for (int off = 1; off < 16; off <<= 1) {
                s  += __shfl_xor(s, off, 64);
                sq += __shfl_xor(sq, off, 64);
            }
            float mean = s * (1.0f / DIM);
            float var  = sq * (1.0f / DIM) - mean * mean;
            float rstd = rsqrtf(var + LN_EPS);
            int node = n0 + w * 16 + quad * 4 + i;
            if (node < N_NODES) {
#pragma unroll
                for (int j = 0; j < 8; ++j) {
                    float v = acc[j][i] + bj[j];
                    v = (v - mean) * rstd * gj[j] + btj[j];
                    out[(size_t)node * DIM + j * 16 + m] = fmaxf(v, 0.f);
                }
            }
        }
    } else {
#pragma unroll
        for (int i = 0; i < 4; ++i) {
            int node = n0 + w * 16 + quad * 4 + i;
            if (node < N_NODES) {
#pragma unroll
                for (int j = 0; j < 8; ++j) {
                    size_t o = (size_t)node * DIM + j * 16 + m;
                    float v = acc[j][i];
                    if (accumulate) v += out[o];
                    out[o] = v;
                }
            }
        }
    }
}

// ---------------------------------------------------------------------------
// Standalone bias + LayerNorm + ReLU (fallback for chunked path).
// ---------------------------------------------------------------------------
__global__ __launch_bounds__(256) void ln_kernel(float* __restrict__ out,
                                                 const float* __restrict__ bias,
                                                 const float* __restrict__ gamma,
                                                 const float* __restrict__ beta) {
    int row  = blockIdx.x * 4 + (threadIdx.x >> 6);
    int lane = threadIdx.x & 63;
    if (row >= N_NODES) return;
    float2 v = *(float2*)(out + (size_t)row * DIM + lane * 2);
    float2 bi = *(const float2*)(bias + lane * 2);
    v.x += bi.x;
    v.y += bi.y;
    float s  = v.x + v.y;
    float sq = v.x * v.x + v.y * v.y;
#pragma unroll
    for (int off = 32; off > 0; off >>= 1) {
        s  += __shfl_xor(s, off, 64);
        sq += __shfl_xor(sq, off, 64);
    }
    float mean = s * (1.0f / DIM);
    float var  = sq * (1.0f / DIM) - mean * mean;
    float rstd = rsqrtf(var + LN_EPS);
    float2 g = *(const float2*)(gamma + lane * 2);
    float2 b = *(const float2*)(beta + lane * 2);
    v.x = fmaxf((v.x - mean) * rstd * g.x + b.x, 0.f);
    v.y = fmaxf((v.y - mean) * rstd * g.y + b.y, 0.f);
    *(float2*)(out + (size_t)row * DIM + lane * 2) = v;
}

// ---------------------------------------------------------------------------
extern "C" void kernel_launch(void* const* d_in, const int* in_sizes, int n_in,
                              void* d_out, int out_size, void* d_ws, size_t ws_size,
                              hipStream_t stream) {
    const float* x      = (const float*)d_in[0];
    const int*   ei     = (const int*)d_in[1];
    const int*   et     = (const int*)d_in[2];
    const float* W_rel  = (const float*)d_in[4];
    const float* W_root = (const float*)d_in[5];
    const float* bias   = (const float*)d_in[6];
    const float* gamma  = (const float*)d_in[7];
    const float* beta   = (const float*)d_in[8];
    float*       out    = (float*)d_out;

    // ---- workspace layout ----
    char* ws = (char*)d_ws;
    size_t off = 0;
    auto alloc = [&](size_t bytes) { char* p = ws + off; off = (off + bytes + 255) & ~(size_t)255; return p; };
    unsigned* cnt        = (unsigned*)alloc((size_t)NKEYS * 4);   // NKEYS*4 is 256-aligned
    unsigned* done       = (unsigned*)alloc(256);                 // adjacent to cnt
    uint2*    meta       = (uint2*)alloc((size_t)NKEYS * 8);
    unsigned* bsums      = (unsigned*)alloc((size_t)SCAN_NBLK * 4);
    unsigned* krk        = (unsigned*)alloc((size_t)N_EDGES * 4);
    int*      sorted_src = (int*)alloc((size_t)N_EDGES * 4);
    ushort_t* Bt         = (ushort_t*)alloc((size_t)9 * DIM * DIM * 2);
    ushort_t* xb         = (ushort_t*)alloc((size_t)N_NODES * DIM * 2);
    size_t fixedOff = off;
    ushort_t* h = (ushort_t*)(ws + fixedOff);
    size_t availB = ws_size > fixedOff ? ws_size - fixedOff : 0;
    size_t perRel = (size_t)N_NODES * DIM * 2;   // 12.8 MB per relation (bf16)
    int chunkR = (int)(availB / perRel);
    if (chunkR > NREL) chunkR = NREL;
    if (chunkR < 1)    chunkR = 1;

    // ---- build counting sort: memset -> prep+count -> scan(2-in-1) -> fill ----
    hipMemsetAsync(cnt, 0, (size_t)NKEYS * 4 + 256, stream);   // cnt + done counter
    prep_count_kernel<<<XB_BLOCKS + BT_BLOCKS + CNT_BLOCKS, 256, 0, stream>>>(
        x, xb, W_rel, W_root, Bt, ei, et, cnt, krk);
    scan_kernel<<<SCAN_NBLK, 256, 0, stream>>>(cnt, meta, bsums, done);
    fill_kernel<<<(N_EDGES + 255) / 256, 256, 0, stream>>>(ei, krk, meta, bsums, sorted_src);

    int gemmGrid = (N_NODES + 63) / 64;

    if (chunkR >= NREL) {
        int nbuck = N_NODES * NREL;
        aggregate_kernel<<<(nbuck + 7) / 8, 256, 0, stream>>>(meta, bsums, sorted_src,
                                                              xb, h, 0, NREL);
        gemm_ln_kernel<<<gemmGrid, 256, 0, stream>>>(h, NREL, 0, xb, Bt, 1,
                                                     bias, gamma, beta, out, 0, 1);
    } else {
        for (int r0 = 0; r0 < NREL; r0 += chunkR) {
            int cr = (NREL - r0 < chunkR) ? (NREL - r0) : chunkR;
            int nbuck = N_NODES * cr;
            aggregate_kernel<<<(nbuck + 7) / 8, 256, 0, stream>>>(meta, bsums, sorted_src,
                                                                  xb, h, r0, cr);
            int include_root = (r0 + cr == NREL) ? 1 : 0;
            gemm_ln_kernel<<<gemmGrid, 256, 0, stream>>>(h, cr, r0, xb, Bt, include_root,
                                                         bias, gamma, beta, out,
                                                         r0 > 0 ? 1 : 0, 0);
        }
        ln_kernel<<<(N_NODES + 3) / 4, 256, 0, stream>>>(out, bias, gamma, beta);
    }
}

// Round 11
// 352.327 us; speedup vs baseline: 2.1754x; 1.1061x over previous
//
#include <hip/hip_runtime.h>
#include <hip/hip_bf16.h>
#include <cstdint>

#define N_NODES 50000
#define N_EDGES 1600000
#define DIM 128
#define NREL 8
#define LN_EPS 1e-5f

#define NKEYS (N_NODES * NREL)          // 400000
#define SCAN_CHUNK 1024                 // keys per scan block (256 thr x 4)
#define SCAN_NBLK ((NKEYS + SCAN_CHUNK - 1) / SCAN_CHUNK)  // 391

#define A_STRIDE 136                    // ushorts per LDS A row (128 + 8 pad)
#define B_STRIDE 136                    // ushorts per LDS B row

#define XB_BLOCKS 6250                  // N_NODES*DIM/4 / 256
#define BT_BLOCKS 576                   // 9*128*128 / 256

typedef unsigned short ushort_t;
typedef short short8 __attribute__((ext_vector_type(8)));
typedef float f32x4 __attribute__((ext_vector_type(4)));
typedef unsigned uintx4 __attribute__((ext_vector_type(4)));

__device__ inline ushort_t f2bf(float f) {
    union { float f; unsigned u; } v; v.f = f;
    unsigned r = (v.u + 0x7FFFu + ((v.u >> 16) & 1u)) >> 16;
    return (ushort_t)r;
}
__device__ inline float bf_lo(unsigned u) {
    union { unsigned u; float f; } v; v.u = u << 16;
    return v.f;
}
__device__ inline float bf_hi(unsigned u) {
    union { unsigned u; float f; } v; v.u = u & 0xffff0000u;
    return v.f;
}

// ---------------------------------------------------------------------------
// Fused prep: xb (x fp32 -> bf16) and Bt (W transposed bf16), one launch.
// ---------------------------------------------------------------------------
__global__ __launch_bounds__(256) void prep_kernel(const float* __restrict__ x,
                                                   ushort_t* __restrict__ xb,
                                                   const float* __restrict__ W_rel,
                                                   const float* __restrict__ W_root,
                                                   ushort_t* __restrict__ Bt) {
    int b = blockIdx.x;
    if (b < XB_BLOCKS) {
        int i = b * 256 + threadIdx.x;            // float4 index
        float4 v = ((const float4*)x)[i];
        unsigned lo = (unsigned)f2bf(v.x) | ((unsigned)f2bf(v.y) << 16);
        unsigned hi = (unsigned)f2bf(v.z) | ((unsigned)f2bf(v.w) << 16);
        ((uint2*)xb)[i] = make_uint2(lo, hi);
    } else {
        int i = (b - XB_BLOCKS) * 256 + threadIdx.x;
        int r   = i >> 14;
        int rem = i & 16383;
        int n   = rem >> 7;
        int k   = rem & 127;
        const float* W = (r < NREL) ? (W_rel + (size_t)r * DIM * DIM) : W_root;
        Bt[i] = f2bf(W[(size_t)k * DIM + n]);
    }
}

// ---------------------------------------------------------------------------
// Count edges per key AND record each edge's within-bucket rank, packed as
// (key << 13) | rank.
// ---------------------------------------------------------------------------
__global__ __launch_bounds__(256) void count_rank_kernel(const int* __restrict__ ei,
                                                         const int* __restrict__ et,
                                                         unsigned* __restrict__ cnt,
                                                         unsigned* __restrict__ krk) {
    int e = blockIdx.x * 256 + threadIdx.x;
    if (e < N_EDGES) {
        int dst = ei[N_EDGES + e];
        unsigned key = (unsigned)dst * NREL + (unsigned)et[e];
        unsigned rank = atomicAdd(&cnt[key], 1u);
        krk[e] = (key << 13) | rank;
    }
}

// ---------------------------------------------------------------------------
// Block-local exclusive scan: meta[key] = (local_excl_offset, cnt), plus
// per-block sums. Consumers add bsums[key>>10] for the global offset.
// ---------------------------------------------------------------------------
__global__ __launch_bounds__(256) void scan1_kernel(const unsigned* __restrict__ cnt,
                                                    uint2* __restrict__ meta,
                                                    unsigned* __restrict__ bsums) {
    __shared__ unsigned lds[256];
    int tid = threadIdx.x;
    int i0  = blockIdx.x * SCAN_CHUNK + tid * 4;
    unsigned v[4], incl[4];
    unsigned s = 0;
#pragma unroll
    for (int j = 0; j < 4; ++j) {
        v[j] = (i0 + j < NKEYS) ? cnt[i0 + j] : 0u;
        s += v[j];
        incl[j] = s;
    }
    lds[tid] = s;
    __syncthreads();
    for (int off = 1; off < 256; off <<= 1) {
        unsigned a = (tid >= off) ? lds[tid - off] : 0u;
        __syncthreads();
        lds[tid] += a;
        __syncthreads();
    }
    unsigned base = lds[tid] - s;
#pragma unroll
    for (int j = 0; j < 4; ++j) {
        if (i0 + j < NKEYS) meta[i0 + j] = make_uint2(base + incl[j] - v[j], v[j]);
    }
    if (tid == 255) bsums[blockIdx.x] = lds[255];
}

__global__ __launch_bounds__(512) void scan2_kernel(unsigned* __restrict__ bsums) {
    __shared__ unsigned lds[512];
    int tid = threadIdx.x;
    unsigned v = (tid < SCAN_NBLK) ? bsums[tid] : 0u;
    lds[tid] = v;
    __syncthreads();
    for (int off = 1; off < 512; off <<= 1) {
        unsigned a = (tid >= off) ? lds[tid - off] : 0u;
        __syncthreads();
        lds[tid] += a;
        __syncthreads();
    }
    if (tid < SCAN_NBLK) bsums[tid] = lds[tid] - v;
}

// ---------------------------------------------------------------------------
// Atomic-free counting-sort fill: p = meta[key].x + bsums[key>>10] + rank.
// ---------------------------------------------------------------------------
__global__ __launch_bounds__(256) void fill_kernel(const int* __restrict__ ei,
                                                   const unsigned* __restrict__ krk,
                                                   const uint2* __restrict__ meta,
                                                   const unsigned* __restrict__ bsums,
                                                   int* __restrict__ sorted_src) {
    int e = blockIdx.x * 256 + threadIdx.x;
    if (e < N_EDGES) {
        unsigned kr   = krk[e];
        unsigned key  = kr >> 13;
        unsigned rank = kr & 8191u;
        unsigned p = meta[key].x + bsums[key >> 10] + rank;
        sorted_src[p] = ei[e];
    }
}

// ---------------------------------------------------------------------------
// Half-wave (32 lanes x 8B) per (node, rel) bucket: mean of xb rows -> h bf16.
// Edge walk unrolled 4-deep: 4 independent uint2 loads in flight per iter.
// [R10-measured: 87 us vs 94.5 us for the 2-deep version]
// ---------------------------------------------------------------------------
__global__ __launch_bounds__(256) void aggregate_kernel(const uint2* __restrict__ meta,
                                                        const unsigned* __restrict__ bsums,
                                                        const int* __restrict__ sorted_src,
                                                        const ushort_t* __restrict__ xb,
                                                        ushort_t* __restrict__ h,
                                                        int r0, int cr) {
    int g  = blockIdx.x * 8 + (threadIdx.x >> 5);   // bucket id
    int sl = threadIdx.x & 31;                      // lane covers 4 feats
    int total = N_NODES * cr;
    if (g >= total) return;
    unsigned key;
    if (cr == NREL) {
        key = (unsigned)g;                          // g == node*8 + rel
    } else {
        int n  = g / cr;
        int rl = g - n * cr;
        key = (unsigned)n * NREL + r0 + rl;
    }
    uint2 md = meta[key];
    unsigned st = md.x + bsums[key >> 10];
    unsigned mc = md.y;
    unsigned en = st + mc;
    float a0 = 0.f, a1 = 0.f, a2 = 0.f, a3 = 0.f;
    unsigned e = st;
    for (; e + 3 < en; e += 4) {
        int s0 = sorted_src[e];
        int s1 = sorted_src[e + 1];
        int s2 = sorted_src[e + 2];
        int s3 = sorted_src[e + 3];
        uint2 d0 = *(const uint2*)(xb + (size_t)s0 * DIM + sl * 4);
        uint2 d1 = *(const uint2*)(xb + (size_t)s1 * DIM + sl * 4);
        uint2 d2 = *(const uint2*)(xb + (size_t)s2 * DIM + sl * 4);
        uint2 d3 = *(const uint2*)(xb + (size_t)s3 * DIM + sl * 4);
        a0 += (bf_lo(d0.x) + bf_lo(d1.x)) + (bf_lo(d2.x) + bf_lo(d3.x));
        a1 += (bf_hi(d0.x) + bf_hi(d1.x)) + (bf_hi(d2.x) + bf_hi(d3.x));
        a2 += (bf_lo(d0.y) + bf_lo(d1.y)) + (bf_lo(d2.y) + bf_lo(d3.y));
        a3 += (bf_hi(d0.y) + bf_hi(d1.y)) + (bf_hi(d2.y) + bf_hi(d3.y));
    }
    if (e + 1 < en) {
        int s0 = sorted_src[e];
        int s1 = sorted_src[e + 1];
        uint2 d0 = *(const uint2*)(xb + (size_t)s0 * DIM + sl * 4);
        uint2 d1 = *(const uint2*)(xb + (size_t)s1 * DIM + sl * 4);
        a0 += bf_lo(d0.x) + bf_lo(d1.x);
        a1 += bf_hi(d0.x) + bf_hi(d1.x);
        a2 += bf_lo(d0.y) + bf_lo(d1.y);
        a3 += bf_hi(d0.y) + bf_hi(d1.y);
        e += 2;
    }
    if (e < en) {
        int s0 = sorted_src[e];
        uint2 d0 = *(const uint2*)(xb + (size_t)s0 * DIM + sl * 4);
        a0 += bf_lo(d0.x);
        a1 += bf_hi(d0.x);
        a2 += bf_lo(d0.y);
        a3 += bf_hi(d0.y);
    }
    float inv = 1.0f / fmaxf((float)mc, 1.0f);
    unsigned lo = (unsigned)f2bf(a0 * inv) | ((unsigned)f2bf(a1 * inv) << 16);
    unsigned hi = (unsigned)f2bf(a2 * inv) | ((unsigned)f2bf(a3 * inv) << 16);
    ((uint2*)(h + (size_t)g * DIM))[sl] = make_uint2(lo, hi);
}

// ---------------------------------------------------------------------------
// LDS-staged MFMA GEMM + optional fused bias+LN+ReLU. 64 nodes x 128 feats,
// 4 waves, ~52 KB LDS, 3 blocks/CU. Plain (cached) loads throughout.
// ---------------------------------------------------------------------------
__global__ __launch_bounds__(256) void gemm_ln_kernel(const ushort_t* __restrict__ h,
                                                      int cr, int r0,
                                                      const ushort_t* __restrict__ xb,
                                                      const ushort_t* __restrict__ Bt,
                                                      int include_root,
                                                      const float* __restrict__ bias,
                                                      const float* __restrict__ gamma,
                                                      const float* __restrict__ beta,
                                                      float* __restrict__ out,
                                                      int accumulate, int do_ln) {
    __shared__ __align__(16) ushort_t As[64 * A_STRIDE];
    __shared__ __align__(16) ushort_t Bs[128 * B_STRIDE];

    int tid  = threadIdx.x;
    int w    = tid >> 6;
    int lane = tid & 63;
    int m    = lane & 15;
    int quad = lane >> 4;
    int n0   = blockIdx.x * 64;

    f32x4 acc[8];
#pragma unroll
    for (int j = 0; j < 8; ++j) acc[j] = (f32x4){0.f, 0.f, 0.f, 0.f};

    int nrel = cr + include_root;
    for (int rr = 0; rr < nrel; ++rr) {
        int rel = (rr < cr) ? (r0 + rr) : NREL;

        // ---- stage B: 2048 x 16B chunks, 8 per thread (batched) ----
#pragma unroll
        for (int p = 0; p < 8; ++p) {
            int c = tid + 256 * p;
            int row = c >> 4, ch = c & 15;
            uintx4 v = *(const uintx4*)(Bt + ((size_t)rel * DIM + row) * DIM + ch * 8);
            *(uintx4*)&Bs[row * B_STRIDE + ch * 8] = v;
        }
        // ---- stage A: 1024 x 16B chunks, 4 per thread (batched) ----
#pragma unroll
        for (int p = 0; p < 4; ++p) {
            int c = tid + 256 * p;
            int row = c >> 4, ch = c & 15;
            uintx4 v = (uintx4){0u, 0u, 0u, 0u};
            int node = n0 + row;
            if (node < N_NODES) {
                const ushort_t* src = (rr < cr)
                    ? (h + ((size_t)node * cr + rr) * DIM)
                    : (xb + (size_t)node * DIM);
                v = *(const uintx4*)(src + ch * 8);
            }
            *(uintx4*)&As[row * A_STRIDE + ch * 8] = v;
        }
        __syncthreads();

        // ---- 32 MFMA per wave ----
#pragma unroll
        for (int t = 0; t < 4; ++t) {
            short8 af = *(const short8*)&As[(w * 16 + m) * A_STRIDE + t * 32 + quad * 8];
#pragma unroll
            for (int j = 0; j < 8; ++j) {
                short8 bf = *(const short8*)&Bs[(j * 16 + m) * B_STRIDE + t * 32 + quad * 8];
                acc[j] = __builtin_amdgcn_mfma_f32_16x16x32_bf16(af, bf, acc[j], 0, 0, 0);
            }
        }
        __syncthreads();
    }

    // ---- epilogue ----
    if (do_ln) {
        float bj[8], gj[8], btj[8];
#pragma unroll
        for (int j = 0; j < 8; ++j) {
            bj[j]  = bias[j * 16 + m];
            gj[j]  = gamma[j * 16 + m];
            btj[j] = beta[j * 16 + m];
        }
#pragma unroll
        for (int i = 0; i < 4; ++i) {
            float s = 0.f, sq = 0.f;
#pragma unroll
            for (int j = 0; j < 8; ++j) {
                float v = acc[j][i] + bj[j];
                s  += v;
                sq += v * v;
            }
#pragma unroll
            for (int off = 1; off < 16; off <<= 1) {
                s  += __shfl_xor(s, off, 64);
                sq += __shfl_xor(sq, off, 64);
            }
            float mean = s * (1.0f / DIM);
            float var  = sq * (1.0f / DIM) - mean * mean;
            float rstd = rsqrtf(var + LN_EPS);
            int node = n0 + w * 16 + quad * 4 + i;
            if (node < N_NODES) {
#pragma unroll
                for (int j = 0; j < 8; ++j) {
                    float v = acc[j][i] + bj[j];
                    v = (v - mean) * rstd * gj[j] + btj[j];
                    out[(size_t)node * DIM + j * 16 + m] = fmaxf(v, 0.f);
                }
            }
        }
    } else {
#pragma unroll
        for (int i = 0; i < 4; ++i) {
            int node = n0 + w * 16 + quad * 4 + i;
            if (node < N_NODES) {
#pragma unroll
                for (int j = 0; j < 8; ++j) {
                    size_t o = (size_t)node * DIM + j * 16 + m;
                    float v = acc[j][i];
                    if (accumulate) v += out[o];
                    out[o] = v;
                }
            }
        }
    }
}

// ---------------------------------------------------------------------------
// Standalone bias + LayerNorm + ReLU (fallback for chunked path).
// ---------------------------------------------------------------------------
__global__ __launch_bounds__(256) void ln_kernel(float* __restrict__ out,
                                                 const float* __restrict__ bias,
                                                 const float* __restrict__ gamma,
                                                 const float* __restrict__ beta) {
    int row  = blockIdx.x * 4 + (threadIdx.x >> 6);
    int lane = threadIdx.x & 63;
    if (row >= N_NODES) return;
    float2 v = *(float2*)(out + (size_t)row * DIM + lane * 2);
    float2 bi = *(const float2*)(bias + lane * 2);
    v.x += bi.x;
    v.y += bi.y;
    float s  = v.x + v.y;
    float sq = v.x * v.x + v.y * v.y;
#pragma unroll
    for (int off = 32; off > 0; off >>= 1) {
        s  += __shfl_xor(s, off, 64);
        sq += __shfl_xor(sq, off, 64);
    }
    float mean = s * (1.0f / DIM);
    float var  = sq * (1.0f / DIM) - mean * mean;
    float rstd = rsqrtf(var + LN_EPS);
    float2 g = *(const float2*)(gamma + lane * 2);
    float2 b = *(const float2*)(beta + lane * 2);
    v.x = fmaxf((v.x - mean) * rstd * g.x + b.x, 0.f);
    v.y = fmaxf((v.y - mean) * rstd * g.y + b.y, 0.f);
    *(float2*)(out + (size_t)row * DIM + lane * 2) = v;
}

// ---------------------------------------------------------------------------
extern "C" void kernel_launch(void* const* d_in, const int* in_sizes, int n_in,
                              void* d_out, int out_size, void* d_ws, size_t ws_size,
                              hipStream_t stream) {
    const float* x      = (const float*)d_in[0];
    const int*   ei     = (const int*)d_in[1];
    const int*   et     = (const int*)d_in[2];
    const float* W_rel  = (const float*)d_in[4];
    const float* W_root = (const float*)d_in[5];
    const float* bias   = (const float*)d_in[6];
    const float* gamma  = (const float*)d_in[7];
    const float* beta   = (const float*)d_in[8];
    float*       out    = (float*)d_out;

    // ---- workspace layout ----
    char* ws = (char*)d_ws;
    size_t off = 0;
    auto alloc = [&](size_t bytes) { char* p = ws + off; off = (off + bytes + 255) & ~(size_t)255; return p; };
    unsigned* cnt        = (unsigned*)alloc((size_t)NKEYS * 4);
    uint2*    meta       = (uint2*)alloc((size_t)NKEYS * 8);
    unsigned* bsums      = (unsigned*)alloc((size_t)SCAN_NBLK * 4);
    unsigned* krk        = (unsigned*)alloc((size_t)N_EDGES * 4);
    int*      sorted_src = (int*)alloc((size_t)N_EDGES * 4);
    ushort_t* Bt         = (ushort_t*)alloc((size_t)9 * DIM * DIM * 2);
    ushort_t* xb         = (ushort_t*)alloc((size_t)N_NODES * DIM * 2);
    size_t fixedOff = off;
    ushort_t* h = (ushort_t*)(ws + fixedOff);
    size_t availB = ws_size > fixedOff ? ws_size - fixedOff : 0;
    size_t perRel = (size_t)N_NODES * DIM * 2;   // 12.8 MB per relation (bf16)
    int chunkR = (int)(availB / perRel);
    if (chunkR > NREL) chunkR = NREL;
    if (chunkR < 1)    chunkR = 1;

    // ---- build counting sort (rank recorded during count; no fill atomic) ----
    hipMemsetAsync(cnt, 0, (size_t)NKEYS * 4, stream);
    prep_kernel<<<XB_BLOCKS + BT_BLOCKS, 256, 0, stream>>>(x, xb, W_rel, W_root, Bt);
    count_rank_kernel<<<(N_EDGES + 255) / 256, 256, 0, stream>>>(ei, et, cnt, krk);
    scan1_kernel<<<SCAN_NBLK, 256, 0, stream>>>(cnt, meta, bsums);
    scan2_kernel<<<1, 512, 0, stream>>>(bsums);
    fill_kernel<<<(N_EDGES + 255) / 256, 256, 0, stream>>>(ei, krk, meta, bsums, sorted_src);

    int gemmGrid = (N_NODES + 63) / 64;

    if (chunkR >= NREL) {
        int nbuck = N_NODES * NREL;
        aggregate_kernel<<<(nbuck + 7) / 8, 256, 0, stream>>>(meta, bsums, sorted_src,
                                                              xb, h, 0, NREL);
        gemm_ln_kernel<<<gemmGrid, 256, 0, stream>>>(h, NREL, 0, xb, Bt, 1,
                                                     bias, gamma, beta, out, 0, 1);
    } else {
        for (int r0 = 0; r0 < NREL; r0 += chunkR) {
            int cr = (NREL - r0 < chunkR) ? (NREL - r0) : chunkR;
            int nbuck = N_NODES * cr;
            aggregate_kernel<<<(nbuck + 7) / 8, 256, 0, stream>>>(meta, bsums, sorted_src,
                                                                  xb, h, r0, cr);
            int include_root = (r0 + cr == NREL) ? 1 : 0;
            gemm_ln_kernel<<<gemmGrid, 256, 0, stream>>>(h, cr, r0, xb, Bt, include_root,
                                                         bias, gamma, beta, out,
                                                         r0 > 0 ? 1 : 0, 0);
        }
        ln_kernel<<<(N_NODES + 3) / 4, 256, 0, stream>>>(out, bias, gamma, beta);
    }
}

// Round 12
// 335.937 us; speedup vs baseline: 2.2815x; 1.0488x over previous
//
#include <hip/hip_runtime.h>
#include <hip/hip_bf16.h>
#include <cstdint>

#define N_NODES 50000
#define N_EDGES 1600000
#define DIM 128
#define NREL 8
#define LN_EPS 1e-5f

#define NKEYS (N_NODES * NREL)          // 400000
#define SCAN_CHUNK 1024                 // keys per scan block (256 thr x 4)
#define SCAN_NBLK ((NKEYS + SCAN_CHUNK - 1) / SCAN_CHUNK)  // 391

#define A_STRIDE 136                    // ushorts per LDS A row (128 + 8 pad)
#define B_STRIDE 136                    // ushorts per LDS B row

#define XB_BLOCKS 6250                  // N_NODES*DIM/4 / 256
#define BT_BLOCKS 576                   // 9*128*128 / 256

typedef unsigned short ushort_t;
typedef short short8 __attribute__((ext_vector_type(8)));
typedef float f32x4 __attribute__((ext_vector_type(4)));
typedef unsigned uintx4 __attribute__((ext_vector_type(4)));

__device__ inline ushort_t f2bf(float f) {
    union { float f; unsigned u; } v; v.f = f;
    unsigned r = (v.u + 0x7FFFu + ((v.u >> 16) & 1u)) >> 16;
    return (ushort_t)r;
}
__device__ inline float bf_lo(unsigned u) {
    union { unsigned u; float f; } v; v.u = u << 16;
    return v.f;
}
__device__ inline float bf_hi(unsigned u) {
    union { unsigned u; float f; } v; v.u = u & 0xffff0000u;
    return v.f;
}

// ---------------------------------------------------------------------------
// Fused prep: xb (x fp32 -> bf16) and Bt (W transposed bf16), one launch.
// ---------------------------------------------------------------------------
__global__ __launch_bounds__(256) void prep_kernel(const float* __restrict__ x,
                                                   ushort_t* __restrict__ xb,
                                                   const float* __restrict__ W_rel,
                                                   const float* __restrict__ W_root,
                                                   ushort_t* __restrict__ Bt) {
    int b = blockIdx.x;
    if (b < XB_BLOCKS) {
        int i = b * 256 + threadIdx.x;            // float4 index
        float4 v = ((const float4*)x)[i];
        unsigned lo = (unsigned)f2bf(v.x) | ((unsigned)f2bf(v.y) << 16);
        unsigned hi = (unsigned)f2bf(v.z) | ((unsigned)f2bf(v.w) << 16);
        ((uint2*)xb)[i] = make_uint2(lo, hi);
    } else {
        int i = (b - XB_BLOCKS) * 256 + threadIdx.x;
        int r   = i >> 14;
        int rem = i & 16383;
        int n   = rem >> 7;
        int k   = rem & 127;
        const float* W = (r < NREL) ? (W_rel + (size_t)r * DIM * DIM) : W_root;
        Bt[i] = f2bf(W[(size_t)k * DIM + n]);
    }
}

// ---------------------------------------------------------------------------
// Count edges per key AND record each edge's within-bucket rank, packed as
// (key << 13) | rank.
// ---------------------------------------------------------------------------
__global__ __launch_bounds__(256) void count_rank_kernel(const int* __restrict__ ei,
                                                         const int* __restrict__ et,
                                                         unsigned* __restrict__ cnt,
                                                         unsigned* __restrict__ krk) {
    int e = blockIdx.x * 256 + threadIdx.x;
    if (e < N_EDGES) {
        int dst = ei[N_EDGES + e];
        unsigned key = (unsigned)dst * NREL + (unsigned)et[e];
        unsigned rank = atomicAdd(&cnt[key], 1u);
        krk[e] = (key << 13) | rank;
    }
}

// ---------------------------------------------------------------------------
// Block-local exclusive scan: meta[key] = (local_excl_offset, cnt), plus
// per-block sums. Consumers add bsums[key>>10] for the global offset.
// ---------------------------------------------------------------------------
__global__ __launch_bounds__(256) void scan1_kernel(const unsigned* __restrict__ cnt,
                                                    uint2* __restrict__ meta,
                                                    unsigned* __restrict__ bsums) {
    __shared__ unsigned lds[256];
    int tid = threadIdx.x;
    int i0  = blockIdx.x * SCAN_CHUNK + tid * 4;
    unsigned v[4], incl[4];
    unsigned s = 0;
#pragma unroll
    for (int j = 0; j < 4; ++j) {
        v[j] = (i0 + j < NKEYS) ? cnt[i0 + j] : 0u;
        s += v[j];
        incl[j] = s;
    }
    lds[tid] = s;
    __syncthreads();
    for (int off = 1; off < 256; off <<= 1) {
        unsigned a = (tid >= off) ? lds[tid - off] : 0u;
        __syncthreads();
        lds[tid] += a;
        __syncthreads();
    }
    unsigned base = lds[tid] - s;
#pragma unroll
    for (int j = 0; j < 4; ++j) {
        if (i0 + j < NKEYS) meta[i0 + j] = make_uint2(base + incl[j] - v[j], v[j]);
    }
    if (tid == 255) bsums[blockIdx.x] = lds[255];
}

__global__ __launch_bounds__(512) void scan2_kernel(unsigned* __restrict__ bsums) {
    __shared__ unsigned lds[512];
    int tid = threadIdx.x;
    unsigned v = (tid < SCAN_NBLK) ? bsums[tid] : 0u;
    lds[tid] = v;
    __syncthreads();
    for (int off = 1; off < 512; off <<= 1) {
        unsigned a = (tid >= off) ? lds[tid - off] : 0u;
        __syncthreads();
        lds[tid] += a;
        __syncthreads();
    }
    if (tid < SCAN_NBLK) bsums[tid] = lds[tid] - v;
}

// ---------------------------------------------------------------------------
// Atomic-free counting-sort fill: p = meta[key].x + bsums[key>>10] + rank.
// ---------------------------------------------------------------------------
__global__ __launch_bounds__(256) void fill_kernel(const int* __restrict__ ei,
                                                   const unsigned* __restrict__ krk,
                                                   const uint2* __restrict__ meta,
                                                   const unsigned* __restrict__ bsums,
                                                   int* __restrict__ sorted_src) {
    int e = blockIdx.x * 256 + threadIdx.x;
    if (e < N_EDGES) {
        unsigned kr   = krk[e];
        unsigned key  = kr >> 13;
        unsigned rank = kr & 8191u;
        unsigned p = meta[key].x + bsums[key >> 10] + rank;
        sorted_src[p] = ei[e];
    }
}

// ---------------------------------------------------------------------------
// Half-wave (32 lanes x 8B) per (node, rel) bucket: mean of xb rows -> h bf16.
// Edge walk unrolled 4-deep: 4 independent uint2 loads in flight per iter.
// [R10/R11-measured: 86-87 us]
// ---------------------------------------------------------------------------
__global__ __launch_bounds__(256) void aggregate_kernel(const uint2* __restrict__ meta,
                                                        const unsigned* __restrict__ bsums,
                                                        const int* __restrict__ sorted_src,
                                                        const ushort_t* __restrict__ xb,
                                                        ushort_t* __restrict__ h,
                                                        int r0, int cr) {
    int g  = blockIdx.x * 8 + (threadIdx.x >> 5);   // bucket id
    int sl = threadIdx.x & 31;                      // lane covers 4 feats
    int total = N_NODES * cr;
    if (g >= total) return;
    unsigned key;
    if (cr == NREL) {
        key = (unsigned)g;                          // g == node*8 + rel
    } else {
        int n  = g / cr;
        int rl = g - n * cr;
        key = (unsigned)n * NREL + r0 + rl;
    }
    uint2 md = meta[key];
    unsigned st = md.x + bsums[key >> 10];
    unsigned mc = md.y;
    unsigned en = st + mc;
    float a0 = 0.f, a1 = 0.f, a2 = 0.f, a3 = 0.f;
    unsigned e = st;
    for (; e + 3 < en; e += 4) {
        int s0 = sorted_src[e];
        int s1 = sorted_src[e + 1];
        int s2 = sorted_src[e + 2];
        int s3 = sorted_src[e + 3];
        uint2 d0 = *(const uint2*)(xb + (size_t)s0 * DIM + sl * 4);
        uint2 d1 = *(const uint2*)(xb + (size_t)s1 * DIM + sl * 4);
        uint2 d2 = *(const uint2*)(xb + (size_t)s2 * DIM + sl * 4);
        uint2 d3 = *(const uint2*)(xb + (size_t)s3 * DIM + sl * 4);
        a0 += (bf_lo(d0.x) + bf_lo(d1.x)) + (bf_lo(d2.x) + bf_lo(d3.x));
        a1 += (bf_hi(d0.x) + bf_hi(d1.x)) + (bf_hi(d2.x) + bf_hi(d3.x));
        a2 += (bf_lo(d0.y) + bf_lo(d1.y)) + (bf_lo(d2.y) + bf_lo(d3.y));
        a3 += (bf_hi(d0.y) + bf_hi(d1.y)) + (bf_hi(d2.y) + bf_hi(d3.y));
    }
    if (e + 1 < en) {
        int s0 = sorted_src[e];
        int s1 = sorted_src[e + 1];
        uint2 d0 = *(const uint2*)(xb + (size_t)s0 * DIM + sl * 4);
        uint2 d1 = *(const uint2*)(xb + (size_t)s1 * DIM + sl * 4);
        a0 += bf_lo(d0.x) + bf_lo(d1.x);
        a1 += bf_hi(d0.x) + bf_hi(d1.x);
        a2 += bf_lo(d0.y) + bf_lo(d1.y);
        a3 += bf_hi(d0.y) + bf_hi(d1.y);
        e += 2;
    }
    if (e < en) {
        int s0 = sorted_src[e];
        uint2 d0 = *(const uint2*)(xb + (size_t)s0 * DIM + sl * 4);
        a0 += bf_lo(d0.x);
        a1 += bf_hi(d0.x);
        a2 += bf_lo(d0.y);
        a3 += bf_hi(d0.y);
    }
    float inv = 1.0f / fmaxf((float)mc, 1.0f);
    unsigned lo = (unsigned)f2bf(a0 * inv) | ((unsigned)f2bf(a1 * inv) << 16);
    unsigned hi = (unsigned)f2bf(a2 * inv) | ((unsigned)f2bf(a3 * inv) << 16);
    ((uint2*)(h + (size_t)g * DIM))[sl] = make_uint2(lo, hi);
}

// ---------------------------------------------------------------------------
// LDS-staged MFMA GEMM + optional fused bias+LN+ReLU.
// 128 nodes x 128 feats per block, 512 threads (8 waves, each wave 16 nodes
// x 128 feats — identical per-wave job as R11). LDS = 69.6 KB -> 2 blocks/CU
// -> 512 co-resident slots >= 391 blocks: SINGLE generation, no straggler
// tail (R11's 782-block/768-slot config ran a ~full-length 14-block tail).
// ---------------------------------------------------------------------------
__global__ __launch_bounds__(512) void gemm_ln_kernel(const ushort_t* __restrict__ h,
                                                      int cr, int r0,
                                                      const ushort_t* __restrict__ xb,
                                                      const ushort_t* __restrict__ Bt,
                                                      int include_root,
                                                      const float* __restrict__ bias,
                                                      const float* __restrict__ gamma,
                                                      const float* __restrict__ beta,
                                                      float* __restrict__ out,
                                                      int accumulate, int do_ln) {
    __shared__ __align__(16) ushort_t As[128 * A_STRIDE];   // 34.8 KB
    __shared__ __align__(16) ushort_t Bs[128 * B_STRIDE];   // 34.8 KB

    int tid  = threadIdx.x;
    int w    = tid >> 6;          // 0..7
    int lane = tid & 63;
    int m    = lane & 15;
    int quad = lane >> 4;
    int n0   = blockIdx.x * 128;

    f32x4 acc[8];
#pragma unroll
    for (int j = 0; j < 8; ++j) acc[j] = (f32x4){0.f, 0.f, 0.f, 0.f};

    int nrel = cr + include_root;
    for (int rr = 0; rr < nrel; ++rr) {
        int rel = (rr < cr) ? (r0 + rr) : NREL;

        // ---- stage B: 2048 x 16B chunks, 4 per thread (batched) ----
#pragma unroll
        for (int p = 0; p < 4; ++p) {
            int c = tid + 512 * p;
            int row = c >> 4, ch = c & 15;
            uintx4 v = *(const uintx4*)(Bt + ((size_t)rel * DIM + row) * DIM + ch * 8);
            *(uintx4*)&Bs[row * B_STRIDE + ch * 8] = v;
        }
        // ---- stage A: 2048 x 16B chunks (128 rows), 4 per thread ----
#pragma unroll
        for (int p = 0; p < 4; ++p) {
            int c = tid + 512 * p;
            int row = c >> 4, ch = c & 15;
            uintx4 v = (uintx4){0u, 0u, 0u, 0u};
            int node = n0 + row;
            if (node < N_NODES) {
                const ushort_t* src = (rr < cr)
                    ? (h + ((size_t)node * cr + rr) * DIM)
                    : (xb + (size_t)node * DIM);
                v = *(const uintx4*)(src + ch * 8);
            }
            *(uintx4*)&As[row * A_STRIDE + ch * 8] = v;
        }
        __syncthreads();

        // ---- 32 MFMA per wave ----
#pragma unroll
        for (int t = 0; t < 4; ++t) {
            short8 af = *(const short8*)&As[(w * 16 + m) * A_STRIDE + t * 32 + quad * 8];
#pragma unroll
            for (int j = 0; j < 8; ++j) {
                short8 bf = *(const short8*)&Bs[(j * 16 + m) * B_STRIDE + t * 32 + quad * 8];
                acc[j] = __builtin_amdgcn_mfma_f32_16x16x32_bf16(af, bf, acc[j], 0, 0, 0);
            }
        }
        __syncthreads();
    }

    // ---- epilogue ----
    if (do_ln) {
        float bj[8], gj[8], btj[8];
#pragma unroll
        for (int j = 0; j < 8; ++j) {
            bj[j]  = bias[j * 16 + m];
            gj[j]  = gamma[j * 16 + m];
            btj[j] = beta[j * 16 + m];
        }
#pragma unroll
        for (int i = 0; i < 4; ++i) {
            float s = 0.f, sq = 0.f;
#pragma unroll
            for (int j = 0; j < 8; ++j) {
                float v = acc[j][i] + bj[j];
                s  += v;
                sq += v * v;
            }
#pragma unroll
            for (int off = 1; off < 16; off <<= 1) {
                s  += __shfl_xor(s, off, 64);
                sq += __shfl_xor(sq, off, 64);
            }
            float mean = s * (1.0f / DIM);
            float var  = sq * (1.0f / DIM) - mean * mean;
            float rstd = rsqrtf(var + LN_EPS);
            int node = n0 + w * 16 + quad * 4 + i;
            if (node < N_NODES) {
#pragma unroll
                for (int j = 0; j < 8; ++j) {
                    float v = acc[j][i] + bj[j];
                    v = (v - mean) * rstd * gj[j] + btj[j];
                    out[(size_t)node * DIM + j * 16 + m] = fmaxf(v, 0.f);
                }
            }
        }
    } else {
#pragma unroll
        for (int i = 0; i < 4; ++i) {
            int node = n0 + w * 16 + quad * 4 + i;
            if (node < N_NODES) {
#pragma unroll
                for (int j = 0; j < 8; ++j) {
                    size_t o = (size_t)node * DIM + j * 16 + m;
                    float v = acc[j][i];
                    if (accumulate) v += out[o];
                    out[o] = v;
                }
            }
        }
    }
}

// ---------------------------------------------------------------------------
// Standalone bias + LayerNorm + ReLU (fallback for chunked path).
// ---------------------------------------------------------------------------
__global__ __launch_bounds__(256) void ln_kernel(float* __restrict__ out,
                                                 const float* __restrict__ bias,
                                                 const float* __restrict__ gamma,
                                                 const float* __restrict__ beta) {
    int row  = blockIdx.x * 4 + (threadIdx.x >> 6);
    int lane = threadIdx.x & 63;
    if (row >= N_NODES) return;
    float2 v = *(float2*)(out + (size_t)row * DIM + lane * 2);
    float2 bi = *(const float2*)(bias + lane * 2);
    v.x += bi.x;
    v.y += bi.y;
    float s  = v.x + v.y;
    float sq = v.x * v.x + v.y * v.y;
#pragma unroll
    for (int off = 32; off > 0; off >>= 1) {
        s  += __shfl_xor(s, off, 64);
        sq += __shfl_xor(sq, off, 64);
    }
    float mean = s * (1.0f / DIM);
    float var  = sq * (1.0f / DIM) - mean * mean;
    float rstd = rsqrtf(var + LN_EPS);
    float2 g = *(const float2*)(gamma + lane * 2);
    float2 b = *(const float2*)(beta + lane * 2);
    v.x = fmaxf((v.x - mean) * rstd * g.x + b.x, 0.f);
    v.y = fmaxf((v.y - mean) * rstd * g.y + b.y, 0.f);
    *(float2*)(out + (size_t)row * DIM + lane * 2) = v;
}

// ---------------------------------------------------------------------------
extern "C" void kernel_launch(void* const* d_in, const int* in_sizes, int n_in,
                              void* d_out, int out_size, void* d_ws, size_t ws_size,
                              hipStream_t stream) {
    const float* x      = (const float*)d_in[0];
    const int*   ei     = (const int*)d_in[1];
    const int*   et     = (const int*)d_in[2];
    const float* W_rel  = (const float*)d_in[4];
    const float* W_root = (const float*)d_in[5];
    const float* bias   = (const float*)d_in[6];
    const float* gamma  = (const float*)d_in[7];
    const float* beta   = (const float*)d_in[8];
    float*       out    = (float*)d_out;

    // ---- workspace layout ----
    char* ws = (char*)d_ws;
    size_t off = 0;
    auto alloc = [&](size_t bytes) { char* p = ws + off; off = (off + bytes + 255) & ~(size_t)255; return p; };
    unsigned* cnt        = (unsigned*)alloc((size_t)NKEYS * 4);
    uint2*    meta       = (uint2*)alloc((size_t)NKEYS * 8);
    unsigned* bsums      = (unsigned*)alloc((size_t)SCAN_NBLK * 4);
    unsigned* krk        = (unsigned*)alloc((size_t)N_EDGES * 4);
    int*      sorted_src = (int*)alloc((size_t)N_EDGES * 4);
    ushort_t* Bt         = (ushort_t*)alloc((size_t)9 * DIM * DIM * 2);
    ushort_t* xb         = (ushort_t*)alloc((size_t)N_NODES * DIM * 2);
    size_t fixedOff = off;
    ushort_t* h = (ushort_t*)(ws + fixedOff);
    size_t availB = ws_size > fixedOff ? ws_size - fixedOff : 0;
    size_t perRel = (size_t)N_NODES * DIM * 2;   // 12.8 MB per relation (bf16)
    int chunkR = (int)(availB / perRel);
    if (chunkR > NREL) chunkR = NREL;
    if (chunkR < 1)    chunkR = 1;

    // ---- build counting sort (rank recorded during count; no fill atomic) ----
    hipMemsetAsync(cnt, 0, (size_t)NKEYS * 4, stream);
    prep_kernel<<<XB_BLOCKS + BT_BLOCKS, 256, 0, stream>>>(x, xb, W_rel, W_root, Bt);
    count_rank_kernel<<<(N_EDGES + 255) / 256, 256, 0, stream>>>(ei, et, cnt, krk);
    scan1_kernel<<<SCAN_NBLK, 256, 0, stream>>>(cnt, meta, bsums);
    scan2_kernel<<<1, 512, 0, stream>>>(bsums);
    fill_kernel<<<(N_EDGES + 255) / 256, 256, 0, stream>>>(ei, krk, meta, bsums, sorted_src);

    int gemmGrid = (N_NODES + 127) / 128;   // 391 blocks, all co-resident

    if (chunkR >= NREL) {
        int nbuck = N_NODES * NREL;
        aggregate_kernel<<<(nbuck + 7) / 8, 256, 0, stream>>>(meta, bsums, sorted_src,
                                                              xb, h, 0, NREL);
        gemm_ln_kernel<<<gemmGrid, 512, 0, stream>>>(h, NREL, 0, xb, Bt, 1,
                                                     bias, gamma, beta, out, 0, 1);
    } else {
        for (int r0 = 0; r0 < NREL; r0 += chunkR) {
            int cr = (NREL - r0 < chunkR) ? (NREL - r0) : chunkR;
            int nbuck = N_NODES * cr;
            aggregate_kernel<<<(nbuck + 7) / 8, 256, 0, stream>>>(meta, bsums, sorted_src,
                                                                  xb, h, r0, cr);
            int include_root = (r0 + cr == NREL) ? 1 : 0;
            gemm_ln_kernel<<<gemmGrid, 512, 0, stream>>>(h, cr, r0, xb, Bt, include_root,
                                                         bias, gamma, beta, out,
                                                         r0 > 0 ? 1 : 0, 0);
        }
        ln_kernel<<<(N_NODES + 3) / 4, 256, 0, stream>>>(out, bias, gamma, beta);
    }
}